// Round 11
// baseline (467.193 us; speedup 1.0000x reference)
//
#include <hip/hip_runtime.h>

#define N_USERS_C 100000
#define N_NODES_C 150000
#define D 64
#define NB 2344              // ceil(150000/64) fine buckets (compact-row space)
#define NSUP 74              // ceil(150000/2048) super buckets
#define CPAD 16              // global cursor padding: 1 int per 64B line
#define SPAD 68              // transform transposed-tile row stride
#define FCAP 1536            // fixed fine-bucket capacity (mean ~1030)
#define S1B 256              // s1 blocks
#define FRAG 240             // per-(block,super) fragment capacity (mean 128, +10 sigma)
#define S2CAP 2560           // s2 per-block staging capacity
#define BPS 16               // blocks per super in s2
#define FPB (S1B / BPS)      // fragments per s2 block = 16

// ---------------- Needed-set marking ----------------
__global__ __launch_bounds__(256) void mark1_k(
    const int* __restrict__ u, const int* __restrict__ it,
    unsigned char* __restrict__ samp, unsigned char* __restrict__ need,
    int* __restrict__ tcnt, int batch)
{
    int i = blockIdx.x * blockDim.x + threadIdx.x;
    if (i == 0) *tcnt = 0;                 // ticket for scanA last-block
    if (i >= 2 * batch) return;
    int n = (i < batch) ? u[i] : N_USERS_C + it[i - batch];
    samp[n] = 1;
    need[n] = 1;
}

__global__ __launch_bounds__(256) void mark2_k(
    const int* __restrict__ rows, const int* __restrict__ cols,
    const unsigned char* __restrict__ samp, unsigned char* __restrict__ need, int nnz)
{
    int gtid = blockIdx.x * blockDim.x + threadIdx.x;
    int stride = gridDim.x * blockDim.x;
    for (int e = gtid; e < nnz; e += stride)
        if (samp[rows[e]]) need[cols[e]] = 1;
}

// ---------------- scanA: per-block scan + last-block scans the block sums ----------------
__global__ __launch_bounds__(1024) void scanA_k(
    const unsigned char* __restrict__ need, int* __restrict__ part,
    int* __restrict__ bsum, int* __restrict__ tcnt, int* __restrict__ Mptr,
    int n, int nblocks)
{
    __shared__ int wsum[16];
    __shared__ int isLast;
    int i = blockIdx.x * 1024 + threadIdx.x;
    int lane = threadIdx.x & 63, wid = threadIdx.x >> 6;
    int v = (i < n) ? (int)need[i] : 0;
    int incl = v;
    #pragma unroll
    for (int off = 1; off < 64; off <<= 1) {
        int t = __shfl_up(incl, off);
        if (lane >= off) incl += t;
    }
    if (lane == 63) wsum[wid] = incl;
    __syncthreads();
    int woff = 0;
    for (int w = 0; w < wid; ++w) woff += wsum[w];
    if (i < n) part[i] = woff + incl - v;
    if (threadIdx.x == 1023) bsum[blockIdx.x] = woff + incl;

    // last block performs the 147-element exclusive scan of bsum
    __threadfence();
    if (threadIdx.x == 0) isLast = (atomicAdd(tcnt, 1) == nblocks - 1);
    __syncthreads();
    if (!isLast) return;
    __threadfence();
    int j = threadIdx.x;
    int bv = (j < nblocks) ? atomicAdd(&bsum[j], 0) : 0;   // device-coherent read
    int bincl = bv;
    #pragma unroll
    for (int off = 1; off < 64; off <<= 1) {
        int t = __shfl_up(bincl, off);
        if (lane >= off) bincl += t;
    }
    __syncthreads();                        // wsum reuse barrier
    if (lane == 63) wsum[wid] = bincl;
    __syncthreads();
    int woff2 = 0;
    for (int w = 0; w < wid; ++w) woff2 += wsum[w];
    if (j < nblocks) bsum[j] = woff2 + bincl - bv;
    if (j == nblocks - 1) Mptr[0] = woff2 + bincl;
}

// ---------------- scanB: finalize idx/list + init fine-bucket cursors ----------------
__global__ __launch_bounds__(256) void scanB_k(
    const int* __restrict__ bsum, int* __restrict__ idx,
    const unsigned char* __restrict__ need, int* __restrict__ list,
    int* __restrict__ bcur, int n)
{
    int i = blockIdx.x * blockDim.x + threadIdx.x;
    if (i < NB) bcur[i * CPAD] = i * FCAP;
    if (i >= n) return;
    int t = idx[i] + bsum[i >> 10];
    if (need[i]) { idx[i] = t; list[t] = i; }
    else idx[i] = -1;
}

// ---------------- S1: single-pass scatter into private per-(block,super) fragments ----------------
__global__ __launch_bounds__(512) void s1_k(
    const int* __restrict__ rows, const int* __restrict__ cols,
    const float* __restrict__ vals, const int* __restrict__ idx,
    int2* __restrict__ pairs1, int* __restrict__ scnt, int nnz)
{
    __shared__ int lcur[NSUP];
    int t = threadIdx.x;
    for (int i = t; i < NSUP; i += 512) lcur[i] = 0;
    __syncthreads();
    int b = blockIdx.x;
    int per = (nnz + S1B - 1) / S1B;
    int s = b * per;
    int e = min(nnz, s + per);
    for (int i = s + t; i < e; i += 512) {
        int ci = idx[rows[i]];
        if (ci < 0) continue;
        int sp = ci >> 11;
        int k = atomicAdd(&lcur[sp], 1);
        pairs1[(size_t)sp * (S1B * FRAG) + b * FRAG + k] =
            make_int2(((ci & 2047) << 18) | cols[i], __float_as_int(vals[i]));
    }
    __syncthreads();
    for (int i = t; i < NSUP; i += 512) scnt[i * S1B + b] = lcur[i];
}

// ---------------- S2: gather fragments of one super-part, scatter to fine buckets ----------------
__global__ __launch_bounds__(256) void s2_k(
    const int* __restrict__ scnt, const int2* __restrict__ pairs1,
    int* __restrict__ bcurP, int2* __restrict__ pairs)
{
    __shared__ int2 sbuf[S2CAP];
    __shared__ int fcnt[32], fcur[32], gb[32];
    int sp = blockIdx.x / BPS, part = blockIdx.x % BPS;
    int t = threadIdx.x;
    if (t < 32) { fcnt[t] = 0; fcur[t] = 0; }
    __syncthreads();
    int base = 0;
    for (int fi = 0; fi < FPB; ++fi) {
        int b = part * FPB + fi;
        int m = scnt[sp * S1B + b];
        const int2* src = &pairs1[(size_t)sp * (S1B * FRAG) + b * FRAG];
        for (int i = t; i < m; i += 256) {
            int2 p = src[i];
            sbuf[base + i] = p;
            atomicAdd(&fcnt[(p.x >> 18) >> 6], 1);
        }
        base += m;
    }
    __syncthreads();
    if (t < 32) {
        int c = fcnt[t];
        gb[t] = c ? atomicAdd(&bcurP[(sp * 32 + t) * CPAD], c) : 0;
    }
    __syncthreads();
    for (int i = t; i < base; i += 256) {
        int2 p = sbuf[i];
        int ris = p.x >> 18;
        int f = ris >> 6;
        int k = atomicAdd(&fcur[f], 1);
        pairs[gb[f] + k] = make_int2(((ris & 63) << 18) | (p.x & 0x3FFFF), p.y);
    }
}

// ---------------- gs1: per-bucket LDS sort + layer-1 row gathers (fused) ----------------
// Writes sorted pairs + rp back (for gt2), and side rows for the bucket.
__global__ __launch_bounds__(256) void gs1_k(
    const int* __restrict__ bcurP, int2* __restrict__ pairs,
    int* __restrict__ rp, const float* __restrict__ x,
    float* __restrict__ side, const int* __restrict__ Mptr)
{
    __shared__ int2 buf[FCAP];
    __shared__ int2 obuf[FCAP];
    __shared__ int cnt[64], cur[64], rs[65];
    int b = blockIdx.x;
    if (b * 64 >= Mptr[0]) return;
    int s = b * FCAP;
    int m = bcurP[b * CPAD] - s;
    int t = threadIdx.x, lane = t & 63, wid = t >> 6;
    if (t < 64) cnt[t] = 0;
    __syncthreads();
    for (int i = t; i < m; i += 256) {
        int2 p = pairs[s + i];
        buf[i] = p;
        atomicAdd(&cnt[p.x >> 18], 1);
    }
    __syncthreads();
    if (t < 64) {
        int v = cnt[t], incl = v;
        #pragma unroll
        for (int o = 1; o < 64; o <<= 1) {
            int u = __shfl_up(incl, o);
            if (t >= o) incl += u;
        }
        rs[t] = incl - v;
        cur[t] = incl - v;
        rp[b * 65 + t] = s + incl - v;
        if (t == 63) { rs[64] = incl; rp[b * 65 + 64] = s + incl; }
    }
    __syncthreads();
    for (int i = t; i < m; i += 256) {
        int2 p = buf[i];
        int dst = atomicAdd(&cur[p.x >> 18], 1);
        obuf[dst] = make_int2(p.x & 0x3FFFF, p.y);
    }
    __syncthreads();
    for (int i = t; i < m; i += 256)        // sorted write-back for gt2
        pairs[s + i] = obuf[i];

    // row gathers: wave wid handles rows wid*16 .. wid*16+15; lane = dim
    for (int j = wid * 16; j < wid * 16 + 16; ++j) {
        int k  = rs[j];
        int re = rs[j + 1];
        float acc = 0.0f;
        for (; k + 8 <= re; k += 8) {
            float vv[8], ff[8];
            #pragma unroll
            for (int q = 0; q < 8; ++q) {
                int2 p = obuf[k + q];       // LDS broadcast (same addr all lanes)
                vv[q] = __int_as_float(p.y);
                ff[q] = x[(size_t)p.x * D + lane];
            }
            #pragma unroll
            for (int q = 0; q < 8; ++q) acc = fmaf(vv[q], ff[q], acc);
        }
        for (; k < re; ++k) {
            int2 p = obuf[k];
            acc = fmaf(__int_as_float(p.y), x[(size_t)p.x * D + lane], acc);
        }
        side[((size_t)b * 64 + j) * D + lane] = acc;
    }
}

// ---------------- Tiled transform (layer 1) ----------------
__global__ __launch_bounds__(256) void transform_k(
    const float* __restrict__ S, const float* __restrict__ Eb,
    const float* __restrict__ Wg, const float* __restrict__ bg,
    const float* __restrict__ Wb, const float* __restrict__ bb,
    float* __restrict__ out, const int* __restrict__ list,
    const int* __restrict__ Mptr)
{
    __shared__ __align__(16) float sWg[D * D];
    __shared__ __align__(16) float sWb[D * D];
    __shared__ __align__(16) float sAT[D][SPAD];
    __shared__ __align__(16) float sBT[D][SPAD];

    int nr = Mptr[0];
    int t  = threadIdx.x;
    int tc = t & 15;
    int tr = t >> 4;
    int r0 = blockIdx.x * 64;
    if (r0 >= nr) return;

    for (int i = t; i < D * D; i += 256) {
        sWg[i] = Wg[i];
        sWb[i] = Wb[i];
    }
    for (int itr = 0; itr < 4; ++itr) {
        int rr  = itr * 16 + (t >> 4);
        int row = r0 + rr;
        float4 sv = make_float4(0.f, 0.f, 0.f, 0.f);
        float4 ev = sv;
        if (row < nr) {
            sv = *(const float4*)&S[(size_t)row * D + tc * 4];
            ev = *(const float4*)&Eb[(size_t)list[row] * D + tc * 4];
        }
        sAT[tc * 4 + 0][rr] = sv.x;
        sAT[tc * 4 + 1][rr] = sv.y;
        sAT[tc * 4 + 2][rr] = sv.z;
        sAT[tc * 4 + 3][rr] = sv.w;
        sBT[tc * 4 + 0][rr] = sv.x * ev.x;
        sBT[tc * 4 + 1][rr] = sv.y * ev.y;
        sBT[tc * 4 + 2][rr] = sv.z * ev.z;
        sBT[tc * 4 + 3][rr] = sv.w * ev.w;
    }
    __syncthreads();

    float acc[4][4] = {};
    for (int k = 0; k < D; ++k) {
        float4 a4 = *(const float4*)&sAT[k][tr * 4];
        float4 b4 = *(const float4*)&sBT[k][tr * 4];
        float4 g4 = *(const float4*)&sWg[k * D + tc * 4];
        float4 w4 = *(const float4*)&sWb[k * D + tc * 4];
        float av[4] = {a4.x, a4.y, a4.z, a4.w};
        float bv[4] = {b4.x, b4.y, b4.z, b4.w};
        float gv[4] = {g4.x, g4.y, g4.z, g4.w};
        float wv[4] = {w4.x, w4.y, w4.z, w4.w};
        #pragma unroll
        for (int i = 0; i < 4; ++i)
            #pragma unroll
            for (int j = 0; j < 4; ++j)
                acc[i][j] = fmaf(av[i], gv[j], fmaf(bv[i], wv[j], acc[i][j]));
    }

    float4 bgv = *(const float4*)&bg[tc * 4];
    float4 bbv = *(const float4*)&bb[tc * 4];
    float bias[4] = {bgv.x + bbv.x, bgv.y + bbv.y, bgv.z + bbv.z, bgv.w + bbv.w};

    float vv[4][4];
    float ss[4] = {0.f, 0.f, 0.f, 0.f};
    #pragma unroll
    for (int i = 0; i < 4; ++i) {
        #pragma unroll
        for (int j = 0; j < 4; ++j) {
            float v = acc[i][j] + bias[j];
            v = (v > 0.0f) ? v : 0.2f * v;
            vv[i][j] = v;
            ss[i] += v * v;
        }
    }
    #pragma unroll
    for (int i = 0; i < 4; ++i) {
        #pragma unroll
        for (int off = 1; off < 16; off <<= 1)
            ss[i] += __shfl_xor(ss[i], off);
    }
    #pragma unroll
    for (int i = 0; i < 4; ++i) {
        int row = r0 + tr * 4 + i;
        if (row < nr) {
            float inv = 1.0f / fmaxf(sqrtf(ss[i]), 1e-12f);
            float4 o = make_float4(vv[i][0] * inv, vv[i][1] * inv,
                                   vv[i][2] * inv, vv[i][3] * inv);
            *(float4*)&out[(size_t)row * D + tc * 4] = o;
        }
    }
}

// ---------------- gt2: fused layer-2 gather + transform (sampled rows) ----------------
__global__ __launch_bounds__(256) void gt2_k(
    const int* __restrict__ rp, const int2* __restrict__ pairs,
    const float* __restrict__ e1c, const int* __restrict__ idx,
    const float* __restrict__ Wg, const float* __restrict__ bg,
    const float* __restrict__ Wb, const float* __restrict__ bb,
    float* __restrict__ e2c, const int* __restrict__ u,
    const int* __restrict__ it, int batch)
{
    __shared__ __align__(16) float sWg[D * D];
    __shared__ __align__(16) float sWb[D * D];
    __shared__ __align__(16) float sAT[D][SPAD];
    __shared__ __align__(16) float sBT[D][SPAD];

    int t = threadIdx.x, lane = t & 63, wid = t >> 6;
    int r0 = blockIdx.x * 64;
    int nr = 2 * batch;
    for (int i = t; i < D * D; i += 256) { sWg[i] = Wg[i]; sWb[i] = Wb[i]; }

    // gather phase: wave wid handles rows j = wid*16 .. +15 (lane = dim)
    for (int jj = 0; jj < 16; ++jj) {
        int j = wid * 16 + jj;
        int r = r0 + j;
        float acc = 0.0f, ev = 0.0f;
        if (r < nr) {
            int n = (r < batch) ? u[r] : N_USERS_C + it[r - batch];
            int cr = idx[n];
            int rb = (cr >> 6) * 65 + (cr & 63);
            int s = rp[rb], ep = rp[rb + 1];
            for (int base = s; base < ep; base += 64) {
                int2 p = make_int2(0, 0);
                if (base + lane < ep) p = pairs[base + lane];
                int cc = min(ep - base, 64);
                for (int q = 0; q < cc; ++q) {
                    int   c = __shfl(p.x, q);
                    float v = __int_as_float(__shfl(p.y, q));
                    acc = fmaf(v, e1c[(size_t)idx[c] * D + lane], acc);
                }
            }
            ev = e1c[(size_t)cr * D + lane];
        }
        sAT[lane][j] = acc;
        sBT[lane][j] = acc * ev;
    }
    __syncthreads();

    // transform phase
    int tc = t & 15;
    int tr = t >> 4;
    float acc[4][4] = {};
    for (int k = 0; k < D; ++k) {
        float4 a4 = *(const float4*)&sAT[k][tr * 4];
        float4 b4 = *(const float4*)&sBT[k][tr * 4];
        float4 g4 = *(const float4*)&sWg[k * D + tc * 4];
        float4 w4 = *(const float4*)&sWb[k * D + tc * 4];
        float av[4] = {a4.x, a4.y, a4.z, a4.w};
        float bv[4] = {b4.x, b4.y, b4.z, b4.w};
        float gv[4] = {g4.x, g4.y, g4.z, g4.w};
        float wv[4] = {w4.x, w4.y, w4.z, w4.w};
        #pragma unroll
        for (int i = 0; i < 4; ++i)
            #pragma unroll
            for (int j = 0; j < 4; ++j)
                acc[i][j] = fmaf(av[i], gv[j], fmaf(bv[i], wv[j], acc[i][j]));
    }
    float4 bgv = *(const float4*)&bg[tc * 4];
    float4 bbv = *(const float4*)&bb[tc * 4];
    float bias[4] = {bgv.x + bbv.x, bgv.y + bbv.y, bgv.z + bbv.z, bgv.w + bbv.w};
    float vv[4][4];
    float ss[4] = {0.f, 0.f, 0.f, 0.f};
    #pragma unroll
    for (int i = 0; i < 4; ++i) {
        #pragma unroll
        for (int j = 0; j < 4; ++j) {
            float v = acc[i][j] + bias[j];
            v = (v > 0.0f) ? v : 0.2f * v;
            vv[i][j] = v;
            ss[i] += v * v;
        }
    }
    #pragma unroll
    for (int i = 0; i < 4; ++i) {
        #pragma unroll
        for (int off = 1; off < 16; off <<= 1)
            ss[i] += __shfl_xor(ss[i], off);
    }
    #pragma unroll
    for (int i = 0; i < 4; ++i) {
        int row = r0 + tr * 4 + i;
        if (row < nr) {
            float inv = 1.0f / fmaxf(sqrtf(ss[i]), 1e-12f);
            float4 o = make_float4(vv[i][0] * inv, vv[i][1] * inv,
                                   vv[i][2] * inv, vv[i][3] * inv);
            *(float4*)&e2c[(size_t)row * D + tc * 4] = o;
        }
    }
}

// ---------------- Readout ----------------
__global__ __launch_bounds__(256) void gamma_k(
    const float* __restrict__ x, const float* __restrict__ e1c,
    const int* __restrict__ idx, const float* __restrict__ e2c,
    const int* __restrict__ users, const int* __restrict__ items,
    float* __restrict__ gamma, int batch)
{
    int gtid = blockIdx.x * blockDim.x + threadIdx.x;
    int wave = gtid >> 6;
    int lane = threadIdx.x & 63;
    if (wave >= batch) return;
    size_t uu = (size_t)users[wave];
    size_t tt = (size_t)(N_USERS_C + items[wave]);
    float acc = x[uu * D + lane] * x[tt * D + lane]
              + e1c[(size_t)idx[uu] * D + lane] * e1c[(size_t)idx[tt] * D + lane]
              + e2c[(size_t)wave * D + lane] * e2c[(size_t)(batch + wave) * D + lane];
    #pragma unroll
    for (int off = 1; off < 64; off <<= 1) acc += __shfl_xor(acc, off);
    if (lane == 0) gamma[wave] = acc;
}

extern "C" void kernel_launch(void* const* d_in, const int* in_sizes, int n_in,
                              void* d_out, int out_size, void* d_ws, size_t ws_size,
                              hipStream_t stream) {
    const int*   rows  = (const int*)d_in[0];
    const int*   cols  = (const int*)d_in[1];
    const float* vals  = (const float*)d_in[2];
    const float* x     = (const float*)d_in[3];
    const int*   users = (const int*)d_in[4];
    const int*   items = (const int*)d_in[5];
    const float* Wg0 = (const float*)d_in[6];
    const float* bg0 = (const float*)d_in[7];
    const float* Wb0 = (const float*)d_in[8];
    const float* bb0 = (const float*)d_in[9];
    const float* Wg1 = (const float*)d_in[10];
    const float* bg1 = (const float*)d_in[11];
    const float* Wb1 = (const float*)d_in[12];
    const float* bb1 = (const float*)d_in[13];

    int nnz   = in_sizes[0];
    int batch = in_sizes[4];
    float* out = (float*)d_out;

    size_t emb = (size_t)N_NODES_C * D;
    float* A      = (float*)d_ws;                  // e1c [M x 64]
    float* Sbuf   = A + emb;                       // side_c; aliases pairs1 / e2c
    int*   bcur   = (int*)(Sbuf + emb);            // NB*CPAD
    int*   rp     = bcur + NB * CPAD;              // NB*65 (+pad)
    int*   idx    = rp + NB * 65 + 2;              // [N]
    int*   list   = idx + N_NODES_C;               // [N]
    int*   bsum   = list + N_NODES_C;              // [1024]
    int*   Mptr   = bsum + 1024;                   // [0]=M, [1]=ticket
    int*   scnt   = Mptr + 4;                      // [NSUP*S1B]
    unsigned char* need = (unsigned char*)(scnt + NSUP * S1B);   // [N]
    unsigned char* samp = need + N_NODES_C;                      // [N]
    int2*  pairs  = (int2*)(((size_t)(samp + N_NODES_C) + 15) & ~(size_t)15);  // NB*FCAP

    int2*  pairs1 = (int2*)Sbuf;                   // build-time only (36.4MB < 38.4MB)
    float* e2c    = Sbuf;                          // after transform1 freed Sbuf

    int nscan = (N_NODES_C + 1023) / 1024;         // 147

    // --- needed-set mark + compact (scan fused: 2 kernels) ---
    hipMemsetAsync(need, 0, 2 * N_NODES_C, stream);
    mark1_k<<<(2 * batch + 255) / 256, 256, 0, stream>>>(users, items, samp, need, Mptr + 1, batch);
    mark2_k<<<1024, 256, 0, stream>>>(rows, cols, samp, need, nnz);
    scanA_k<<<nscan, 1024, 0, stream>>>(need, idx, bsum, Mptr + 1, Mptr, N_NODES_C, nscan);
    scanB_k<<<(N_NODES_C + 255) / 256, 256, 0, stream>>>(bsum, idx, need, list, bcur, N_NODES_C);

    // --- bucket build: private fragments (no global atomics in s1) ---
    s1_k<<<S1B, 512, 0, stream>>>(rows, cols, vals, idx, pairs1, scnt, nnz);
    s2_k<<<NSUP * BPS, 256, 0, stream>>>(scnt, pairs1, bcur, pairs);

    // --- Layer 1: fused sort + gather, then transform ---
    gs1_k<<<NB, 256, 0, stream>>>(bcur, pairs, rp, x, Sbuf, Mptr);
    transform_k<<<(N_NODES_C + 63) / 64, 256, 0, stream>>>(
        Sbuf, x, Wg0, bg0, Wb0, bb0, A, list, Mptr);

    // --- Layer 2: fused gather + transform over 2*batch sampled rows ---
    gt2_k<<<(2 * batch + 63) / 64, 256, 0, stream>>>(
        rp, pairs, A, idx, Wg1, bg1, Wb1, bb1, e2c, users, items, batch);

    // --- Readout ---
    gamma_k<<<(batch * 64 + 255) / 256, 256, 0, stream>>>(
        x, A, idx, e2c, users, items, out, batch);
}

// Round 12
// 319.552 us; speedup vs baseline: 1.4620x; 1.4620x over previous
//
#include <hip/hip_runtime.h>

#define N_USERS_C 100000
#define N_NODES_C 150000
#define D 64
#define NB 2344              // ceil(150000/64) fine buckets (compact-row space)
#define NSUP 74              // ceil(150000/2048) super buckets
#define CPAD 16              // global cursor padding: 1 int per 64B line
#define SPAD 68              // transform transposed-tile row stride
#define FCAP 1536            // fixed fine-bucket capacity (mean ~1030)
#define S1B 256              // s1 blocks
#define FRAG 240             // per-(block,super) fragment capacity (mean 128, +10 sigma)
#define S2CAP 2560           // s2 per-block staging capacity
#define BPS 16               // blocks per super in s2
#define FPB (S1B / BPS)      // fragments per s2 block = 16

// ---------------- Needed-set marking ----------------
__global__ __launch_bounds__(256) void mark1_k(
    const int* __restrict__ u, const int* __restrict__ it,
    unsigned char* __restrict__ samp, unsigned char* __restrict__ need,
    int* __restrict__ tcnt, int batch)
{
    int i = blockIdx.x * blockDim.x + threadIdx.x;
    if (i == 0) *tcnt = 0;                 // ticket for scanA last-block
    if (i >= 2 * batch) return;
    int n = (i < batch) ? u[i] : N_USERS_C + it[i - batch];
    samp[n] = 1;
    need[n] = 1;
}

__global__ __launch_bounds__(256) void mark2_k(
    const int* __restrict__ rows, const int* __restrict__ cols,
    const unsigned char* __restrict__ samp, unsigned char* __restrict__ need, int nnz)
{
    int gtid = blockIdx.x * blockDim.x + threadIdx.x;
    int stride = gridDim.x * blockDim.x;
    for (int e = gtid; e < nnz; e += stride)
        if (samp[rows[e]]) need[cols[e]] = 1;
}

// ---------------- scanA: per-block scan + last-block scans the block sums ----------------
__global__ __launch_bounds__(1024) void scanA_k(
    const unsigned char* __restrict__ need, int* __restrict__ part,
    int* __restrict__ bsum, int* __restrict__ tcnt, int* __restrict__ Mptr,
    int n, int nblocks)
{
    __shared__ int wsum[16];
    __shared__ int isLast;
    int i = blockIdx.x * 1024 + threadIdx.x;
    int lane = threadIdx.x & 63, wid = threadIdx.x >> 6;
    int v = (i < n) ? (int)need[i] : 0;
    int incl = v;
    #pragma unroll
    for (int off = 1; off < 64; off <<= 1) {
        int t = __shfl_up(incl, off);
        if (lane >= off) incl += t;
    }
    if (lane == 63) wsum[wid] = incl;
    __syncthreads();
    int woff = 0;
    for (int w = 0; w < wid; ++w) woff += wsum[w];
    if (i < n) part[i] = woff + incl - v;
    if (threadIdx.x == 1023) bsum[blockIdx.x] = woff + incl;

    __threadfence();
    if (threadIdx.x == 0) isLast = (atomicAdd(tcnt, 1) == nblocks - 1);
    __syncthreads();
    if (!isLast) return;
    __threadfence();
    int j = threadIdx.x;
    int bv = (j < nblocks) ? atomicAdd(&bsum[j], 0) : 0;   // device-coherent read
    int bincl = bv;
    #pragma unroll
    for (int off = 1; off < 64; off <<= 1) {
        int t = __shfl_up(bincl, off);
        if (lane >= off) bincl += t;
    }
    __syncthreads();
    if (lane == 63) wsum[wid] = bincl;
    __syncthreads();
    int woff2 = 0;
    for (int w = 0; w < wid; ++w) woff2 += wsum[w];
    if (j < nblocks) bsum[j] = woff2 + bincl - bv;
    if (j == nblocks - 1) Mptr[0] = woff2 + bincl;
}

// ---------------- scanB: finalize idx/list + init fine-bucket cursors ----------------
__global__ __launch_bounds__(256) void scanB_k(
    const int* __restrict__ bsum, int* __restrict__ idx,
    const unsigned char* __restrict__ need, int* __restrict__ list,
    int* __restrict__ bcur, int n)
{
    int i = blockIdx.x * blockDim.x + threadIdx.x;
    if (i < NB) bcur[i * CPAD] = i * FCAP;
    if (i >= n) return;
    int t = idx[i] + bsum[i >> 10];
    if (need[i]) { idx[i] = t; list[t] = i; }
    else idx[i] = -1;
}

// ---------------- S1: single-pass scatter into private per-(block,super) fragments ----------------
__global__ __launch_bounds__(512) void s1_k(
    const int* __restrict__ rows, const int* __restrict__ cols,
    const float* __restrict__ vals, const int* __restrict__ idx,
    int2* __restrict__ pairs1, int* __restrict__ scnt, int nnz)
{
    __shared__ int lcur[NSUP];
    int t = threadIdx.x;
    for (int i = t; i < NSUP; i += 512) lcur[i] = 0;
    __syncthreads();
    int b = blockIdx.x;
    int per = (nnz + S1B - 1) / S1B;
    int s = b * per;
    int e = min(nnz, s + per);
    for (int i = s + t; i < e; i += 512) {
        int ci = idx[rows[i]];
        if (ci < 0) continue;
        int sp = ci >> 11;
        int k = atomicAdd(&lcur[sp], 1);
        pairs1[(size_t)sp * (S1B * FRAG) + b * FRAG + k] =
            make_int2(((ci & 2047) << 18) | cols[i], __float_as_int(vals[i]));
    }
    __syncthreads();
    for (int i = t; i < NSUP; i += 512) scnt[i * S1B + b] = lcur[i];
}

// ---------------- S2: gather fragments of one super-part, scatter to fine buckets ----------------
__global__ __launch_bounds__(256) void s2_k(
    const int* __restrict__ scnt, const int2* __restrict__ pairs1,
    int* __restrict__ bcurP, int2* __restrict__ pairs)
{
    __shared__ int2 sbuf[S2CAP];
    __shared__ int fcnt[32], fcur[32], gb[32];
    int sp = blockIdx.x / BPS, part = blockIdx.x % BPS;
    int t = threadIdx.x;
    if (t < 32) { fcnt[t] = 0; fcur[t] = 0; }
    __syncthreads();
    int base = 0;
    for (int fi = 0; fi < FPB; ++fi) {
        int b = part * FPB + fi;
        int m = scnt[sp * S1B + b];
        const int2* src = &pairs1[(size_t)sp * (S1B * FRAG) + b * FRAG];
        for (int i = t; i < m; i += 256) {
            int2 p = src[i];
            sbuf[base + i] = p;
            atomicAdd(&fcnt[(p.x >> 18) >> 6], 1);
        }
        base += m;
    }
    __syncthreads();
    if (t < 32) {
        int c = fcnt[t];
        gb[t] = c ? atomicAdd(&bcurP[(sp * 32 + t) * CPAD], c) : 0;
    }
    __syncthreads();
    for (int i = t; i < base; i += 256) {
        int2 p = sbuf[i];
        int ris = p.x >> 18;
        int f = ris >> 6;
        int k = atomicAdd(&fcur[f], 1);
        pairs[gb[f] + k] = make_int2(((ris & 63) << 18) | (p.x & 0x3FFFF), p.y);
    }
}

// ---------------- Per-bucket LDS counting sort -> per-row ranges ----------------
__global__ __launch_bounds__(256) void sortb_k(
    const int* __restrict__ bcurP, int2* __restrict__ pairs,
    int* __restrict__ rp)
{
    __shared__ int2 buf[FCAP];
    __shared__ int cnt[64];
    __shared__ int cur[64];
    int b = blockIdx.x;
    int s = b * FCAP;
    int e = bcurP[b * CPAD];
    int m = e - s;
    int t = threadIdx.x;
    if (t < 64) cnt[t] = 0;
    __syncthreads();
    for (int i = t; i < m; i += 256) {
        int2 p = pairs[s + i];
        buf[i] = p;
        atomicAdd(&cnt[p.x >> 18], 1);
    }
    __syncthreads();
    if (t < 64) {
        int v = cnt[t];
        int incl = v;
        #pragma unroll
        for (int o = 1; o < 64; o <<= 1) {
            int u = __shfl_up(incl, o);
            if (t >= o) incl += u;
        }
        cur[t] = incl - v;
        rp[b * 65 + t] = s + incl - v;
        if (t == 63) rp[b * 65 + 64] = s + incl;
    }
    __syncthreads();
    for (int i = t; i < m; i += 256) {
        int2 p = buf[i];
        int dst = atomicAdd(&cur[p.x >> 18], 1);
        pairs[s + dst] = make_int2(p.x & 0x3FFFF, p.y);
    }
}

// ---------------- Layer-1 gather: one wave per needed (compact) row, unroll-8 ----------------
__global__ __launch_bounds__(256) void gather1_k(
    const int* __restrict__ rp, const int2* __restrict__ pairs,
    const float* __restrict__ x, float* __restrict__ side,
    const int* __restrict__ Mptr)
{
    int gtid = blockIdx.x * blockDim.x + threadIdx.x;
    int wave = gtid >> 6;
    int lane = threadIdx.x & 63;
    if (wave >= Mptr[0]) return;
    int rb = (wave >> 6) * 65 + (wave & 63);
    int s  = rp[rb];
    int ep = rp[rb + 1];

    float acc = 0.0f;
    for (int base = s; base < ep; base += 64) {
        int2 p = make_int2(0, 0);
        if (base + lane < ep) p = pairs[base + lane];
        int cnt8 = (min(ep - base, 64) + 7) & ~7;
        for (int j = 0; j < cnt8; j += 8) {
            int cc[8]; float vv[8], ff[8];
            #pragma unroll
            for (int q = 0; q < 8; ++q) {
                cc[q] = __shfl(p.x, j + q);
                vv[q] = __int_as_float(__shfl(p.y, j + q));
            }
            #pragma unroll
            for (int q = 0; q < 8; ++q)
                ff[q] = x[(size_t)cc[q] * D + lane];
            #pragma unroll
            for (int q = 0; q < 8; ++q)
                acc = fmaf(vv[q], ff[q], acc);
        }
    }
    side[(size_t)wave * D + lane] = acc;
}

// ---------------- Layer-2 gather (sampled): e1 via compact idx ----------------
__global__ __launch_bounds__(256) void gather2_k(
    const int* __restrict__ rp, const int2* __restrict__ pairs,
    const float* __restrict__ e1c, const int* __restrict__ idx,
    float* __restrict__ side2c, float* __restrict__ egoc,
    const int* __restrict__ u, const int* __restrict__ it, int batch)
{
    int gtid = blockIdx.x * blockDim.x + threadIdx.x;
    int wave = gtid >> 6;
    int lane = threadIdx.x & 63;
    if (wave >= 2 * batch) return;
    int n = (wave < batch) ? u[wave] : N_USERS_C + it[wave - batch];
    int cr = idx[n];
    int rb = (cr >> 6) * 65 + (cr & 63);
    int s  = rp[rb];
    int ep = rp[rb + 1];

    float acc = 0.0f;
    for (int base = s; base < ep; base += 64) {
        int2 p = make_int2(0, 0);
        if (base + lane < ep) p = pairs[base + lane];
        int cnt = min(ep - base, 64);
        for (int j = 0; j < cnt; ++j) {
            int   c = __shfl(p.x, j);
            float v = __int_as_float(__shfl(p.y, j));
            acc = fmaf(v, e1c[(size_t)idx[c] * D + lane], acc);
        }
    }
    side2c[(size_t)wave * D + lane] = acc;
    egoc[(size_t)wave * D + lane] = e1c[(size_t)cr * D + lane];
}

// ---------------- Tiled transform ----------------
__global__ __launch_bounds__(256) void transform_k(
    const float* __restrict__ S, const float* __restrict__ Eb,
    const float* __restrict__ Wg, const float* __restrict__ bg,
    const float* __restrict__ Wb, const float* __restrict__ bb,
    float* __restrict__ out, const int* __restrict__ list,
    const int* __restrict__ Mptr, int nrows)
{
    __shared__ __align__(16) float sWg[D * D];
    __shared__ __align__(16) float sWb[D * D];
    __shared__ __align__(16) float sAT[D][SPAD];
    __shared__ __align__(16) float sBT[D][SPAD];

    int nr = Mptr ? Mptr[0] : nrows;
    int t  = threadIdx.x;
    int tc = t & 15;
    int tr = t >> 4;
    int r0 = blockIdx.x * 64;
    if (r0 >= nr) return;

    for (int i = t; i < D * D; i += 256) {
        sWg[i] = Wg[i];
        sWb[i] = Wb[i];
    }
    for (int itr = 0; itr < 4; ++itr) {
        int rr  = itr * 16 + (t >> 4);
        int row = r0 + rr;
        float4 sv = make_float4(0.f, 0.f, 0.f, 0.f);
        float4 ev = sv;
        if (row < nr) {
            sv = *(const float4*)&S[(size_t)row * D + tc * 4];
            int er = list ? list[row] : row;
            ev = *(const float4*)&Eb[(size_t)er * D + tc * 4];
        }
        sAT[tc * 4 + 0][rr] = sv.x;
        sAT[tc * 4 + 1][rr] = sv.y;
        sAT[tc * 4 + 2][rr] = sv.z;
        sAT[tc * 4 + 3][rr] = sv.w;
        sBT[tc * 4 + 0][rr] = sv.x * ev.x;
        sBT[tc * 4 + 1][rr] = sv.y * ev.y;
        sBT[tc * 4 + 2][rr] = sv.z * ev.z;
        sBT[tc * 4 + 3][rr] = sv.w * ev.w;
    }
    __syncthreads();

    float acc[4][4] = {};
    for (int k = 0; k < D; ++k) {
        float4 a4 = *(const float4*)&sAT[k][tr * 4];
        float4 b4 = *(const float4*)&sBT[k][tr * 4];
        float4 g4 = *(const float4*)&sWg[k * D + tc * 4];
        float4 w4 = *(const float4*)&sWb[k * D + tc * 4];
        float av[4] = {a4.x, a4.y, a4.z, a4.w};
        float bv[4] = {b4.x, b4.y, b4.z, b4.w};
        float gv[4] = {g4.x, g4.y, g4.z, g4.w};
        float wv[4] = {w4.x, w4.y, w4.z, w4.w};
        #pragma unroll
        for (int i = 0; i < 4; ++i)
            #pragma unroll
            for (int j = 0; j < 4; ++j)
                acc[i][j] = fmaf(av[i], gv[j], fmaf(bv[i], wv[j], acc[i][j]));
    }

    float4 bgv = *(const float4*)&bg[tc * 4];
    float4 bbv = *(const float4*)&bb[tc * 4];
    float bias[4] = {bgv.x + bbv.x, bgv.y + bbv.y, bgv.z + bbv.z, bgv.w + bbv.w};

    float vv[4][4];
    float ss[4] = {0.f, 0.f, 0.f, 0.f};
    #pragma unroll
    for (int i = 0; i < 4; ++i) {
        #pragma unroll
        for (int j = 0; j < 4; ++j) {
            float v = acc[i][j] + bias[j];
            v = (v > 0.0f) ? v : 0.2f * v;
            vv[i][j] = v;
            ss[i] += v * v;
        }
    }
    #pragma unroll
    for (int i = 0; i < 4; ++i) {
        #pragma unroll
        for (int off = 1; off < 16; off <<= 1)
            ss[i] += __shfl_xor(ss[i], off);
    }
    #pragma unroll
    for (int i = 0; i < 4; ++i) {
        int row = r0 + tr * 4 + i;
        if (row < nr) {
            float inv = 1.0f / fmaxf(sqrtf(ss[i]), 1e-12f);
            float4 o = make_float4(vv[i][0] * inv, vv[i][1] * inv,
                                   vv[i][2] * inv, vv[i][3] * inv);
            *(float4*)&out[(size_t)row * D + tc * 4] = o;
        }
    }
}

// ---------------- Readout ----------------
__global__ __launch_bounds__(256) void gamma_k(
    const float* __restrict__ x, const float* __restrict__ e1c,
    const int* __restrict__ idx, const float* __restrict__ e2c,
    const int* __restrict__ users, const int* __restrict__ items,
    float* __restrict__ gamma, int batch)
{
    int gtid = blockIdx.x * blockDim.x + threadIdx.x;
    int wave = gtid >> 6;
    int lane = threadIdx.x & 63;
    if (wave >= batch) return;
    size_t uu = (size_t)users[wave];
    size_t tt = (size_t)(N_USERS_C + items[wave]);
    float acc = x[uu * D + lane] * x[tt * D + lane]
              + e1c[(size_t)idx[uu] * D + lane] * e1c[(size_t)idx[tt] * D + lane]
              + e2c[(size_t)wave * D + lane] * e2c[(size_t)(batch + wave) * D + lane];
    #pragma unroll
    for (int off = 1; off < 64; off <<= 1) acc += __shfl_xor(acc, off);
    if (lane == 0) gamma[wave] = acc;
}

extern "C" void kernel_launch(void* const* d_in, const int* in_sizes, int n_in,
                              void* d_out, int out_size, void* d_ws, size_t ws_size,
                              hipStream_t stream) {
    const int*   rows  = (const int*)d_in[0];
    const int*   cols  = (const int*)d_in[1];
    const float* vals  = (const float*)d_in[2];
    const float* x     = (const float*)d_in[3];
    const int*   users = (const int*)d_in[4];
    const int*   items = (const int*)d_in[5];
    const float* Wg0 = (const float*)d_in[6];
    const float* bg0 = (const float*)d_in[7];
    const float* Wb0 = (const float*)d_in[8];
    const float* bb0 = (const float*)d_in[9];
    const float* Wg1 = (const float*)d_in[10];
    const float* bg1 = (const float*)d_in[11];
    const float* Wb1 = (const float*)d_in[12];
    const float* bb1 = (const float*)d_in[13];

    int nnz   = in_sizes[0];
    int batch = in_sizes[4];
    float* out = (float*)d_out;

    size_t emb = (size_t)N_NODES_C * D;
    float* A      = (float*)d_ws;                  // e1c [M x 64]
    float* Sbuf   = A + emb;                       // side_c; aliases pairs1 / layer2 compacts
    int*   bcur   = (int*)(Sbuf + emb);            // NB*CPAD
    int*   rp     = bcur + NB * CPAD;              // NB*65 (+pad)
    int*   idx    = rp + NB * 65 + 2;              // [N]
    int*   list   = idx + N_NODES_C;               // [N]
    int*   bsum   = list + N_NODES_C;              // [1024]
    int*   Mptr   = bsum + 1024;                   // [0]=M, [1]=ticket
    int*   scnt   = Mptr + 4;                      // [NSUP*S1B]
    unsigned char* need = (unsigned char*)(scnt + NSUP * S1B);   // [N]
    unsigned char* samp = need + N_NODES_C;                      // [N]
    int2*  pairs  = (int2*)(((size_t)(samp + N_NODES_C) + 15) & ~(size_t)15);  // NB*FCAP

    int2*  pairs1 = (int2*)Sbuf;                   // build-time only (36.4MB < 38.4MB)
    float* side2c = Sbuf;                          // layer-2 compacts (after s2 consumed pairs1)
    float* egoc   = Sbuf + (size_t)2 * 2048 * D;
    float* e2c    = egoc + (size_t)2 * 2048 * D;

    int nscan = (N_NODES_C + 1023) / 1024;         // 147

    // --- needed-set mark + compact (fused scans) ---
    hipMemsetAsync(need, 0, 2 * N_NODES_C, stream);
    mark1_k<<<(2 * batch + 255) / 256, 256, 0, stream>>>(users, items, samp, need, Mptr + 1, batch);
    mark2_k<<<1024, 256, 0, stream>>>(rows, cols, samp, need, nnz);
    scanA_k<<<nscan, 1024, 0, stream>>>(need, idx, bsum, Mptr + 1, Mptr, N_NODES_C, nscan);
    scanB_k<<<(N_NODES_C + 255) / 256, 256, 0, stream>>>(bsum, idx, need, list, bcur, N_NODES_C);

    // --- bucket build: private fragments (no global atomics in s1) ---
    s1_k<<<S1B, 512, 0, stream>>>(rows, cols, vals, idx, pairs1, scnt, nnz);
    s2_k<<<NSUP * BPS, 256, 0, stream>>>(scnt, pairs1, bcur, pairs);
    sortb_k<<<NB, 256, 0, stream>>>(bcur, pairs, rp);

    // --- Layer 1 over M needed rows (worst-case grid, early exit on M) ---
    gather1_k<<<(N_NODES_C * 64 + 255) / 256, 256, 0, stream>>>(
        rp, pairs, x, Sbuf, Mptr);
    transform_k<<<(N_NODES_C + 63) / 64, 256, 0, stream>>>(
        Sbuf, x, Wg0, bg0, Wb0, bb0, A, list, Mptr, 0);

    // --- Layer 2 (sampled 2*batch rows) ---
    gather2_k<<<(2 * batch * 64 + 255) / 256, 256, 0, stream>>>(
        rp, pairs, A, idx, side2c, egoc, users, items, batch);
    transform_k<<<(2 * batch + 63) / 64, 256, 0, stream>>>(
        side2c, egoc, Wg1, bg1, Wb1, bb1, e2c, nullptr, nullptr, 2 * batch);

    // --- Readout ---
    gamma_k<<<(batch * 64 + 255) / 256, 256, 0, stream>>>(
        x, A, idx, e2c, users, items, out, batch);
}

// Round 13
// 277.527 us; speedup vs baseline: 1.6834x; 1.1514x over previous
//
#include <hip/hip_runtime.h>

#define N_USERS_C 100000
#define N_NODES_C 150000
#define D 64
#define NB 2344              // ceil(150000/64) fine buckets (compact-row space)
#define NSUP 74              // ceil(150000/2048) super buckets
#define CPAD 16              // global cursor padding: 1 int per 64B line
#define SPAD 68              // transform transposed-tile row stride
#define FCAP 1536            // fixed fine-bucket capacity (mean ~1030)
#define S1B 256              // s1 blocks
#define FRAG 240             // per-(block,super) fragment capacity (mean 128, +10 sigma)
#define S2CAP 2560           // s2 per-block staging capacity
#define BPS 16               // blocks per super in s2
#define FPB (S1B / BPS)      // fragments per s2 block = 16

// ---------------- Needed-set marking ----------------
__global__ __launch_bounds__(256) void mark1_k(
    const int* __restrict__ u, const int* __restrict__ it,
    unsigned char* __restrict__ samp, unsigned char* __restrict__ need, int batch)
{
    int i = blockIdx.x * blockDim.x + threadIdx.x;
    if (i >= 2 * batch) return;
    int n = (i < batch) ? u[i] : N_USERS_C + it[i - batch];
    samp[n] = 1;
    need[n] = 1;
}

__global__ __launch_bounds__(256) void mark2_k(
    const int* __restrict__ rows, const int* __restrict__ cols,
    const unsigned char* __restrict__ samp, unsigned char* __restrict__ need, int nnz)
{
    int gtid = blockIdx.x * blockDim.x + threadIdx.x;
    int stride = gridDim.x * blockDim.x;
    for (int e = gtid; e < nnz; e += stride)
        if (samp[rows[e]]) need[cols[e]] = 1;
}

// ---------------- 2-kernel scan over need flags (no fences) ----------------
__global__ __launch_bounds__(1024) void scan1_k(
    const unsigned char* __restrict__ need, int* __restrict__ part,
    int* __restrict__ bsum, int n)
{
    __shared__ int wsum[16];
    int i = blockIdx.x * 1024 + threadIdx.x;
    int lane = threadIdx.x & 63, wid = threadIdx.x >> 6;
    int v = (i < n) ? (int)need[i] : 0;
    int incl = v;
    #pragma unroll
    for (int off = 1; off < 64; off <<= 1) {
        int t = __shfl_up(incl, off);
        if (lane >= off) incl += t;
    }
    if (lane == 63) wsum[wid] = incl;
    __syncthreads();
    int woff = 0;
    for (int w = 0; w < wid; ++w) woff += wsum[w];
    if (i < n) part[i] = woff + incl - v;
    if (threadIdx.x == 1023) bsum[blockIdx.x] = woff + incl;
}

__global__ __launch_bounds__(1024) void scan2_k(
    int* __restrict__ bsum, int nb, int* __restrict__ Mptr)
{
    __shared__ int wsum[16];
    int lane = threadIdx.x & 63, wid = threadIdx.x >> 6;
    int i = threadIdx.x;
    int v = (i < nb) ? bsum[i] : 0;
    int incl = v;
    #pragma unroll
    for (int off = 1; off < 64; off <<= 1) {
        int t = __shfl_up(incl, off);
        if (lane >= off) incl += t;
    }
    if (lane == 63) wsum[wid] = incl;
    __syncthreads();
    int woff = 0;
    for (int w = 0; w < wid; ++w) woff += wsum[w];
    if (i < nb) bsum[i] = woff + incl - v;
    if (i == nb - 1) Mptr[0] = woff + incl;
}

// ---------------- scanB: finalize idx/list + init fine-bucket cursors ----------------
__global__ __launch_bounds__(256) void scanB_k(
    const int* __restrict__ bsum, int* __restrict__ idx,
    const unsigned char* __restrict__ need, int* __restrict__ list,
    int* __restrict__ bcur, int n)
{
    int i = blockIdx.x * blockDim.x + threadIdx.x;
    if (i < NB) bcur[i * CPAD] = i * FCAP;
    if (i >= n) return;
    int t = idx[i] + bsum[i >> 10];
    if (need[i]) { idx[i] = t; list[t] = i; }
    else idx[i] = -1;
}

// ---------------- S1: single-pass scatter into private per-(block,super) fragments ----------------
__global__ __launch_bounds__(512) void s1_k(
    const int* __restrict__ rows, const int* __restrict__ cols,
    const float* __restrict__ vals, const int* __restrict__ idx,
    int2* __restrict__ pairs1, int* __restrict__ scnt, int nnz)
{
    __shared__ int lcur[NSUP];
    int t = threadIdx.x;
    for (int i = t; i < NSUP; i += 512) lcur[i] = 0;
    __syncthreads();
    int b = blockIdx.x;
    int per = (nnz + S1B - 1) / S1B;
    int s = b * per;
    int e = min(nnz, s + per);
    for (int i = s + t; i < e; i += 512) {
        int ci = idx[rows[i]];
        if (ci < 0) continue;
        int sp = ci >> 11;
        int k = atomicAdd(&lcur[sp], 1);
        pairs1[(size_t)sp * (S1B * FRAG) + b * FRAG + k] =
            make_int2(((ci & 2047) << 18) | cols[i], __float_as_int(vals[i]));
    }
    __syncthreads();
    for (int i = t; i < NSUP; i += 512) scnt[i * S1B + b] = lcur[i];
}

// ---------------- S2: gather fragments of one super-part, scatter to fine buckets ----------------
__global__ __launch_bounds__(256) void s2_k(
    const int* __restrict__ scnt, const int2* __restrict__ pairs1,
    int* __restrict__ bcurP, int2* __restrict__ pairs)
{
    __shared__ int2 sbuf[S2CAP];
    __shared__ int fcnt[32], fcur[32], gb[32];
    int sp = blockIdx.x / BPS, part = blockIdx.x % BPS;
    int t = threadIdx.x;
    if (t < 32) { fcnt[t] = 0; fcur[t] = 0; }
    __syncthreads();
    int base = 0;
    for (int fi = 0; fi < FPB; ++fi) {
        int b = part * FPB + fi;
        int m = scnt[sp * S1B + b];
        const int2* src = &pairs1[(size_t)sp * (S1B * FRAG) + b * FRAG];
        for (int i = t; i < m; i += 256) {
            int2 p = src[i];
            sbuf[base + i] = p;
            atomicAdd(&fcnt[(p.x >> 18) >> 6], 1);
        }
        base += m;
    }
    __syncthreads();
    if (t < 32) {
        int c = fcnt[t];
        gb[t] = c ? atomicAdd(&bcurP[(sp * 32 + t) * CPAD], c) : 0;
    }
    __syncthreads();
    for (int i = t; i < base; i += 256) {
        int2 p = sbuf[i];
        int ris = p.x >> 18;
        int f = ris >> 6;
        int k = atomicAdd(&fcur[f], 1);
        pairs[gb[f] + k] = make_int2(((ris & 63) << 18) | (p.x & 0x3FFFF), p.y);
    }
}

// ---------------- Per-bucket LDS counting sort -> per-row ranges ----------------
__global__ __launch_bounds__(256) void sortb_k(
    const int* __restrict__ bcurP, int2* __restrict__ pairs,
    int* __restrict__ rp)
{
    __shared__ int2 buf[FCAP];
    __shared__ int cnt[64];
    __shared__ int cur[64];
    int b = blockIdx.x;
    int s = b * FCAP;
    int e = bcurP[b * CPAD];
    int m = e - s;
    int t = threadIdx.x;
    if (t < 64) cnt[t] = 0;
    __syncthreads();
    for (int i = t; i < m; i += 256) {
        int2 p = pairs[s + i];
        buf[i] = p;
        atomicAdd(&cnt[p.x >> 18], 1);
    }
    __syncthreads();
    if (t < 64) {
        int v = cnt[t];
        int incl = v;
        #pragma unroll
        for (int o = 1; o < 64; o <<= 1) {
            int u = __shfl_up(incl, o);
            if (t >= o) incl += u;
        }
        cur[t] = incl - v;
        rp[b * 65 + t] = s + incl - v;
        if (t == 63) rp[b * 65 + 64] = s + incl;
    }
    __syncthreads();
    for (int i = t; i < m; i += 256) {
        int2 p = buf[i];
        int dst = atomicAdd(&cur[p.x >> 18], 1);
        pairs[s + dst] = make_int2(p.x & 0x3FFFF, p.y);
    }
}

// ---------------- Layer-1 gather: one wave per needed (compact) row, unroll-8 ----------------
__global__ __launch_bounds__(256) void gather1_k(
    const int* __restrict__ rp, const int2* __restrict__ pairs,
    const float* __restrict__ x, float* __restrict__ side,
    const int* __restrict__ Mptr)
{
    int gtid = blockIdx.x * blockDim.x + threadIdx.x;
    int wave = gtid >> 6;
    int lane = threadIdx.x & 63;
    if (wave >= Mptr[0]) return;
    int rb = (wave >> 6) * 65 + (wave & 63);
    int s  = rp[rb];
    int ep = rp[rb + 1];

    float acc = 0.0f;
    for (int base = s; base < ep; base += 64) {
        int2 p = make_int2(0, 0);
        if (base + lane < ep) p = pairs[base + lane];
        int cnt8 = (min(ep - base, 64) + 7) & ~7;
        for (int j = 0; j < cnt8; j += 8) {
            int cc[8]; float vv[8], ff[8];
            #pragma unroll
            for (int q = 0; q < 8; ++q) {
                cc[q] = __shfl(p.x, j + q);
                vv[q] = __int_as_float(__shfl(p.y, j + q));
            }
            #pragma unroll
            for (int q = 0; q < 8; ++q)
                ff[q] = x[(size_t)cc[q] * D + lane];
            #pragma unroll
            for (int q = 0; q < 8; ++q)
                acc = fmaf(vv[q], ff[q], acc);
        }
    }
    side[(size_t)wave * D + lane] = acc;
}

// ---------------- Layer-2 gather (sampled): e1 via compact idx ----------------
__global__ __launch_bounds__(256) void gather2_k(
    const int* __restrict__ rp, const int2* __restrict__ pairs,
    const float* __restrict__ e1c, const int* __restrict__ idx,
    float* __restrict__ side2c, float* __restrict__ egoc,
    const int* __restrict__ u, const int* __restrict__ it, int batch)
{
    int gtid = blockIdx.x * blockDim.x + threadIdx.x;
    int wave = gtid >> 6;
    int lane = threadIdx.x & 63;
    if (wave >= 2 * batch) return;
    int n = (wave < batch) ? u[wave] : N_USERS_C + it[wave - batch];
    int cr = idx[n];
    int rb = (cr >> 6) * 65 + (cr & 63);
    int s  = rp[rb];
    int ep = rp[rb + 1];

    float acc = 0.0f;
    for (int base = s; base < ep; base += 64) {
        int2 p = make_int2(0, 0);
        if (base + lane < ep) p = pairs[base + lane];
        int cnt = min(ep - base, 64);
        for (int j = 0; j < cnt; ++j) {
            int   c = __shfl(p.x, j);
            float v = __int_as_float(__shfl(p.y, j));
            acc = fmaf(v, e1c[(size_t)idx[c] * D + lane], acc);
        }
    }
    side2c[(size_t)wave * D + lane] = acc;
    egoc[(size_t)wave * D + lane] = e1c[(size_t)cr * D + lane];
}

// ---------------- Tiled transform ----------------
__global__ __launch_bounds__(256) void transform_k(
    const float* __restrict__ S, const float* __restrict__ Eb,
    const float* __restrict__ Wg, const float* __restrict__ bg,
    const float* __restrict__ Wb, const float* __restrict__ bb,
    float* __restrict__ out, const int* __restrict__ list,
    const int* __restrict__ Mptr, int nrows)
{
    __shared__ __align__(16) float sWg[D * D];
    __shared__ __align__(16) float sWb[D * D];
    __shared__ __align__(16) float sAT[D][SPAD];
    __shared__ __align__(16) float sBT[D][SPAD];

    int nr = Mptr ? Mptr[0] : nrows;
    int t  = threadIdx.x;
    int tc = t & 15;
    int tr = t >> 4;
    int r0 = blockIdx.x * 64;
    if (r0 >= nr) return;

    for (int i = t; i < D * D; i += 256) {
        sWg[i] = Wg[i];
        sWb[i] = Wb[i];
    }
    for (int itr = 0; itr < 4; ++itr) {
        int rr  = itr * 16 + (t >> 4);
        int row = r0 + rr;
        float4 sv = make_float4(0.f, 0.f, 0.f, 0.f);
        float4 ev = sv;
        if (row < nr) {
            sv = *(const float4*)&S[(size_t)row * D + tc * 4];
            int er = list ? list[row] : row;
            ev = *(const float4*)&Eb[(size_t)er * D + tc * 4];
        }
        sAT[tc * 4 + 0][rr] = sv.x;
        sAT[tc * 4 + 1][rr] = sv.y;
        sAT[tc * 4 + 2][rr] = sv.z;
        sAT[tc * 4 + 3][rr] = sv.w;
        sBT[tc * 4 + 0][rr] = sv.x * ev.x;
        sBT[tc * 4 + 1][rr] = sv.y * ev.y;
        sBT[tc * 4 + 2][rr] = sv.z * ev.z;
        sBT[tc * 4 + 3][rr] = sv.w * ev.w;
    }
    __syncthreads();

    float acc[4][4] = {};
    for (int k = 0; k < D; ++k) {
        float4 a4 = *(const float4*)&sAT[k][tr * 4];
        float4 b4 = *(const float4*)&sBT[k][tr * 4];
        float4 g4 = *(const float4*)&sWg[k * D + tc * 4];
        float4 w4 = *(const float4*)&sWb[k * D + tc * 4];
        float av[4] = {a4.x, a4.y, a4.z, a4.w};
        float bv[4] = {b4.x, b4.y, b4.z, b4.w};
        float gv[4] = {g4.x, g4.y, g4.z, g4.w};
        float wv[4] = {w4.x, w4.y, w4.z, w4.w};
        #pragma unroll
        for (int i = 0; i < 4; ++i)
            #pragma unroll
            for (int j = 0; j < 4; ++j)
                acc[i][j] = fmaf(av[i], gv[j], fmaf(bv[i], wv[j], acc[i][j]));
    }

    float4 bgv = *(const float4*)&bg[tc * 4];
    float4 bbv = *(const float4*)&bb[tc * 4];
    float bias[4] = {bgv.x + bbv.x, bgv.y + bbv.y, bgv.z + bbv.z, bgv.w + bbv.w};

    float vv[4][4];
    float ss[4] = {0.f, 0.f, 0.f, 0.f};
    #pragma unroll
    for (int i = 0; i < 4; ++i) {
        #pragma unroll
        for (int j = 0; j < 4; ++j) {
            float v = acc[i][j] + bias[j];
            v = (v > 0.0f) ? v : 0.2f * v;
            vv[i][j] = v;
            ss[i] += v * v;
        }
    }
    #pragma unroll
    for (int i = 0; i < 4; ++i) {
        #pragma unroll
        for (int off = 1; off < 16; off <<= 1)
            ss[i] += __shfl_xor(ss[i], off);
    }
    #pragma unroll
    for (int i = 0; i < 4; ++i) {
        int row = r0 + tr * 4 + i;
        if (row < nr) {
            float inv = 1.0f / fmaxf(sqrtf(ss[i]), 1e-12f);
            float4 o = make_float4(vv[i][0] * inv, vv[i][1] * inv,
                                   vv[i][2] * inv, vv[i][3] * inv);
            *(float4*)&out[(size_t)row * D + tc * 4] = o;
        }
    }
}

// ---------------- Readout ----------------
__global__ __launch_bounds__(256) void gamma_k(
    const float* __restrict__ x, const float* __restrict__ e1c,
    const int* __restrict__ idx, const float* __restrict__ e2c,
    const int* __restrict__ users, const int* __restrict__ items,
    float* __restrict__ gamma, int batch)
{
    int gtid = blockIdx.x * blockDim.x + threadIdx.x;
    int wave = gtid >> 6;
    int lane = threadIdx.x & 63;
    if (wave >= batch) return;
    size_t uu = (size_t)users[wave];
    size_t tt = (size_t)(N_USERS_C + items[wave]);
    float acc = x[uu * D + lane] * x[tt * D + lane]
              + e1c[(size_t)idx[uu] * D + lane] * e1c[(size_t)idx[tt] * D + lane]
              + e2c[(size_t)wave * D + lane] * e2c[(size_t)(batch + wave) * D + lane];
    #pragma unroll
    for (int off = 1; off < 64; off <<= 1) acc += __shfl_xor(acc, off);
    if (lane == 0) gamma[wave] = acc;
}

extern "C" void kernel_launch(void* const* d_in, const int* in_sizes, int n_in,
                              void* d_out, int out_size, void* d_ws, size_t ws_size,
                              hipStream_t stream) {
    const int*   rows  = (const int*)d_in[0];
    const int*   cols  = (const int*)d_in[1];
    const float* vals  = (const float*)d_in[2];
    const float* x     = (const float*)d_in[3];
    const int*   users = (const int*)d_in[4];
    const int*   items = (const int*)d_in[5];
    const float* Wg0 = (const float*)d_in[6];
    const float* bg0 = (const float*)d_in[7];
    const float* Wb0 = (const float*)d_in[8];
    const float* bb0 = (const float*)d_in[9];
    const float* Wg1 = (const float*)d_in[10];
    const float* bg1 = (const float*)d_in[11];
    const float* Wb1 = (const float*)d_in[12];
    const float* bb1 = (const float*)d_in[13];

    int nnz   = in_sizes[0];
    int batch = in_sizes[4];
    float* out = (float*)d_out;

    size_t emb = (size_t)N_NODES_C * D;
    float* A      = (float*)d_ws;                  // e1c [M x 64]
    float* Sbuf   = A + emb;                       // side_c; aliases pairs1 / layer2 compacts
    int*   bcur   = (int*)(Sbuf + emb);            // NB*CPAD
    int*   rp     = bcur + NB * CPAD;              // NB*65 (+pad)
    int*   idx    = rp + NB * 65 + 2;              // [N]
    int*   list   = idx + N_NODES_C;               // [N]
    int*   bsum   = list + N_NODES_C;              // [1024]
    int*   Mptr   = bsum + 1024;                   // [4]
    int*   scnt   = Mptr + 4;                      // [NSUP*S1B]
    unsigned char* need = (unsigned char*)(scnt + NSUP * S1B);   // [N]
    unsigned char* samp = need + N_NODES_C;                      // [N]
    int2*  pairs  = (int2*)(((size_t)(samp + N_NODES_C) + 15) & ~(size_t)15);  // NB*FCAP

    int2*  pairs1 = (int2*)Sbuf;                   // build-time only (36.4MB < 38.4MB)
    float* side2c = Sbuf;                          // layer-2 compacts (after s2 consumed pairs1)
    float* egoc   = Sbuf + (size_t)2 * 2048 * D;
    float* e2c    = egoc + (size_t)2 * 2048 * D;

    int nscan = (N_NODES_C + 1023) / 1024;         // 147

    // --- needed-set mark + compact (plain 2-kernel scan; no device fences) ---
    hipMemsetAsync(need, 0, 2 * N_NODES_C, stream);
    mark1_k<<<(2 * batch + 255) / 256, 256, 0, stream>>>(users, items, samp, need, batch);
    mark2_k<<<1024, 256, 0, stream>>>(rows, cols, samp, need, nnz);
    scan1_k<<<nscan, 1024, 0, stream>>>(need, idx, bsum, N_NODES_C);
    scan2_k<<<1, 1024, 0, stream>>>(bsum, nscan, Mptr);
    scanB_k<<<(N_NODES_C + 255) / 256, 256, 0, stream>>>(bsum, idx, need, list, bcur, N_NODES_C);

    // --- bucket build: private fragments (no global atomics in s1) ---
    s1_k<<<S1B, 512, 0, stream>>>(rows, cols, vals, idx, pairs1, scnt, nnz);
    s2_k<<<NSUP * BPS, 256, 0, stream>>>(scnt, pairs1, bcur, pairs);
    sortb_k<<<NB, 256, 0, stream>>>(bcur, pairs, rp);

    // --- Layer 1 over M needed rows (worst-case grid, early exit on M) ---
    gather1_k<<<(N_NODES_C * 64 + 255) / 256, 256, 0, stream>>>(
        rp, pairs, x, Sbuf, Mptr);
    transform_k<<<(N_NODES_C + 63) / 64, 256, 0, stream>>>(
        Sbuf, x, Wg0, bg0, Wb0, bb0, A, list, Mptr, 0);

    // --- Layer 2 (sampled 2*batch rows) ---
    gather2_k<<<(2 * batch * 64 + 255) / 256, 256, 0, stream>>>(
        rp, pairs, A, idx, side2c, egoc, users, items, batch);
    transform_k<<<(2 * batch + 63) / 64, 256, 0, stream>>>(
        side2c, egoc, Wg1, bg1, Wb1, bb1, e2c, nullptr, nullptr, 2 * batch);

    // --- Readout ---
    gamma_k<<<(batch * 64 + 255) / 256, 256, 0, stream>>>(
        x, A, idx, e2c, users, items, out, batch);
}

// Round 14
// 262.143 us; speedup vs baseline: 1.7822x; 1.0587x over previous
//
#include <hip/hip_runtime.h>

#define N_USERS_C 100000
#define N_NODES_C 150000
#define D 64
#define NB 2344              // ceil(150000/64) fine buckets (compact-row space)
#define NSUP 74              // ceil(150000/2048) super buckets
#define CPAD 16              // global cursor padding: 1 int per 64B line
#define SPAD 68              // transform transposed-tile row stride
#define FCAP 1536            // fixed fine-bucket capacity (mean ~1030)
#define S1B 256              // s1 blocks
#define FRAG 240             // per-(block,super) fragment capacity (mean 128, +10 sigma)
#define S2CAP 2560           // s2 per-block staging capacity
#define BPS 16               // blocks per super in s2
#define FPB (S1B / BPS)      // fragments per s2 block = 16
#define NSCAN 147            // ceil(150000/1024)

// ---------------- Needed-set marking ----------------
__global__ __launch_bounds__(256) void mark1_k(
    const int* __restrict__ u, const int* __restrict__ it,
    unsigned char* __restrict__ samp, unsigned char* __restrict__ need, int batch)
{
    int i = blockIdx.x * blockDim.x + threadIdx.x;
    if (i >= 2 * batch) return;
    int n = (i < batch) ? u[i] : N_USERS_C + it[i - batch];
    samp[n] = 1;
    need[n] = 1;
}

__global__ __launch_bounds__(256) void mark2_k(
    const int* __restrict__ rows, const int* __restrict__ cols,
    const unsigned char* __restrict__ samp, unsigned char* __restrict__ need, int nnz)
{
    int gtid = blockIdx.x * blockDim.x + threadIdx.x;
    int stride = gridDim.x * blockDim.x;
    for (int e = gtid; e < nnz; e += stride)
        if (samp[rows[e]]) need[cols[e]] = 1;
}

// ---------------- scan1: per-block scan of need flags ----------------
__global__ __launch_bounds__(1024) void scan1_k(
    const unsigned char* __restrict__ need, int* __restrict__ part,
    int* __restrict__ bsum, int n)
{
    __shared__ int wsum[16];
    int i = blockIdx.x * 1024 + threadIdx.x;
    int lane = threadIdx.x & 63, wid = threadIdx.x >> 6;
    int v = (i < n) ? (int)need[i] : 0;
    int incl = v;
    #pragma unroll
    for (int off = 1; off < 64; off <<= 1) {
        int t = __shfl_up(incl, off);
        if (lane >= off) incl += t;
    }
    if (lane == 63) wsum[wid] = incl;
    __syncthreads();
    int woff = 0;
    for (int w = 0; w < wid; ++w) woff += wsum[w];
    if (i < n) part[i] = woff + incl - v;
    if (threadIdx.x == 1023) bsum[blockIdx.x] = woff + incl;
}

// ---------------- scanB: local prefix of bsum + finalize idx/list + cursors + Mptr ----------------
__global__ __launch_bounds__(256) void scanB_k(
    const int* __restrict__ bsum, int* __restrict__ idx,
    const unsigned char* __restrict__ need, int* __restrict__ list,
    int* __restrict__ bcur, int* __restrict__ Mptr, int n)
{
    __shared__ int pre[NSCAN + 1];
    int t = threadIdx.x;
    __shared__ int raw[NSCAN];
    if (t < NSCAN) raw[t] = bsum[t];
    __syncthreads();
    if (t == 0) {
        int run = 0;
        for (int k = 0; k < NSCAN; ++k) { pre[k] = run; run += raw[k]; }
        pre[NSCAN] = run;
    }
    __syncthreads();
    int i = blockIdx.x * blockDim.x + t;
    if (i < NB) bcur[i * CPAD] = i * FCAP;
    if (blockIdx.x == 0 && t == 0) Mptr[0] = pre[NSCAN];
    if (i >= n) return;
    int val = idx[i] + pre[i >> 10];
    if (need[i]) { idx[i] = val; list[val] = i; }
    else idx[i] = -1;
}

// ---------------- S1: single-pass scatter into private per-(block,super) fragments ----------------
__global__ __launch_bounds__(512) void s1_k(
    const int* __restrict__ rows, const int* __restrict__ cols,
    const float* __restrict__ vals, const int* __restrict__ idx,
    int2* __restrict__ pairs1, int* __restrict__ scnt, int nnz)
{
    __shared__ int lcur[NSUP];
    int t = threadIdx.x;
    for (int i = t; i < NSUP; i += 512) lcur[i] = 0;
    __syncthreads();
    int b = blockIdx.x;
    int per = (nnz + S1B - 1) / S1B;
    int s = b * per;
    int e = min(nnz, s + per);
    for (int i = s + t; i < e; i += 512) {
        int ci = idx[rows[i]];
        if (ci < 0) continue;
        int sp = ci >> 11;
        int k = atomicAdd(&lcur[sp], 1);
        pairs1[(size_t)sp * (S1B * FRAG) + b * FRAG + k] =
            make_int2(((ci & 2047) << 18) | cols[i], __float_as_int(vals[i]));
    }
    __syncthreads();
    for (int i = t; i < NSUP; i += 512) scnt[i * S1B + b] = lcur[i];
}

// ---------------- S2: gather fragments of one super-part, scatter to fine buckets ----------------
__global__ __launch_bounds__(256) void s2_k(
    const int* __restrict__ scnt, const int2* __restrict__ pairs1,
    int* __restrict__ bcurP, int2* __restrict__ pairs)
{
    __shared__ int2 sbuf[S2CAP];
    __shared__ int fcnt[32], fcur[32], gb[32];
    int sp = blockIdx.x / BPS, part = blockIdx.x % BPS;
    int t = threadIdx.x;
    if (t < 32) { fcnt[t] = 0; fcur[t] = 0; }
    __syncthreads();
    int base = 0;
    for (int fi = 0; fi < FPB; ++fi) {
        int b = part * FPB + fi;
        int m = scnt[sp * S1B + b];
        const int2* src = &pairs1[(size_t)sp * (S1B * FRAG) + b * FRAG];
        for (int i = t; i < m; i += 256) {
            int2 p = src[i];
            sbuf[base + i] = p;
            atomicAdd(&fcnt[(p.x >> 18) >> 6], 1);
        }
        base += m;
    }
    __syncthreads();
    if (t < 32) {
        int c = fcnt[t];
        gb[t] = c ? atomicAdd(&bcurP[(sp * 32 + t) * CPAD], c) : 0;
    }
    __syncthreads();
    for (int i = t; i < base; i += 256) {
        int2 p = sbuf[i];
        int ris = p.x >> 18;
        int f = ris >> 6;
        int k = atomicAdd(&fcur[f], 1);
        pairs[gb[f] + k] = make_int2(((ris & 63) << 18) | (p.x & 0x3FFFF), p.y);
    }
}

// ---------------- Per-bucket LDS counting sort -> per-row ranges ----------------
__global__ __launch_bounds__(256) void sortb_k(
    const int* __restrict__ bcurP, int2* __restrict__ pairs,
    int* __restrict__ rp)
{
    __shared__ int2 buf[FCAP];
    __shared__ int cnt[64];
    __shared__ int cur[64];
    int b = blockIdx.x;
    int s = b * FCAP;
    int e = bcurP[b * CPAD];
    int m = e - s;
    int t = threadIdx.x;
    if (t < 64) cnt[t] = 0;
    __syncthreads();
    for (int i = t; i < m; i += 256) {
        int2 p = pairs[s + i];
        buf[i] = p;
        atomicAdd(&cnt[p.x >> 18], 1);
    }
    __syncthreads();
    if (t < 64) {
        int v = cnt[t];
        int incl = v;
        #pragma unroll
        for (int o = 1; o < 64; o <<= 1) {
            int u = __shfl_up(incl, o);
            if (t >= o) incl += u;
        }
        cur[t] = incl - v;
        rp[b * 65 + t] = s + incl - v;
        if (t == 63) rp[b * 65 + 64] = s + incl;
    }
    __syncthreads();
    for (int i = t; i < m; i += 256) {
        int2 p = buf[i];
        int dst = atomicAdd(&cur[p.x >> 18], 1);
        pairs[s + dst] = make_int2(p.x & 0x3FFFF, p.y);
    }
}

// ---------------- Layer-1 gather: quarter-wave float4 — 4 rows/wave, 16 lanes/row ----------------
__global__ __launch_bounds__(256) void gather1_k(
    const int* __restrict__ rp, const int2* __restrict__ pairs,
    const float* __restrict__ x, float* __restrict__ side,
    const int* __restrict__ Mptr)
{
    int gtid = blockIdx.x * blockDim.x + threadIdx.x;
    int wave = gtid >> 6;
    int lane = threadIdx.x & 63;
    int M = Mptr[0];
    if (wave * 4 >= M) return;
    int lq = lane & 15;          // lane within quarter (float4 chunk index)
    int qb = lane & 48;          // quarter base lane
    int row = wave * 4 + (lane >> 4);
    int valid = row < M;
    int s = 0, len = 0;
    if (valid) {
        int rb = (row >> 6) * 65 + (row & 63);
        s = rp[rb];
        len = rp[rb + 1] - s;
    }
    // wave-uniform chunk count
    int ml = len;
    ml = max(ml, __shfl_xor(ml, 16));
    ml = max(ml, __shfl_xor(ml, 32));

    float4 acc = make_float4(0.f, 0.f, 0.f, 0.f);
    for (int base = 0; base < ml; base += 16) {
        int2 p = make_int2(0, 0);
        int o = base + lq;
        if (o < len) p = pairs[s + o];
        int rem = len - base;
        rem = min(max(rem, 0), 16);
        int mr = rem;
        mr = max(mr, __shfl_xor(mr, 16));
        mr = max(mr, __shfl_xor(mr, 32));
        int cnt4 = (mr + 3) & ~3;
        for (int j = 0; j < cnt4; j += 4) {
            int c[4]; float v[4]; float4 f[4];
            #pragma unroll
            for (int q = 0; q < 4; ++q) {
                c[q] = __shfl(p.x, qb | (j + q));
                v[q] = __int_as_float(__shfl(p.y, qb | (j + q)));
            }
            #pragma unroll
            for (int q = 0; q < 4; ++q)
                f[q] = *(const float4*)&x[(size_t)c[q] * D + lq * 4];
            #pragma unroll
            for (int q = 0; q < 4; ++q) {
                acc.x = fmaf(v[q], f[q].x, acc.x);
                acc.y = fmaf(v[q], f[q].y, acc.y);
                acc.z = fmaf(v[q], f[q].z, acc.z);
                acc.w = fmaf(v[q], f[q].w, acc.w);
            }
        }
    }
    if (valid) *(float4*)&side[(size_t)row * D + lq * 4] = acc;
}

// ---------------- Layer-2 gather (sampled): quarter-wave float4 + idx indirection ----------------
__global__ __launch_bounds__(256) void gather2_k(
    const int* __restrict__ rp, const int2* __restrict__ pairs,
    const float* __restrict__ e1c, const int* __restrict__ idx,
    float* __restrict__ side2c, float* __restrict__ egoc,
    const int* __restrict__ u, const int* __restrict__ it, int batch)
{
    int gtid = blockIdx.x * blockDim.x + threadIdx.x;
    int wave = gtid >> 6;
    int lane = threadIdx.x & 63;
    int nr = 2 * batch;
    if (wave * 4 >= nr) return;
    int lq = lane & 15;
    int qb = lane & 48;
    int r = wave * 4 + (lane >> 4);
    int valid = r < nr;
    int s = 0, len = 0, cr = 0;
    if (valid) {
        int n = (r < batch) ? u[r] : N_USERS_C + it[r - batch];
        cr = idx[n];
        int rb = (cr >> 6) * 65 + (cr & 63);
        s = rp[rb];
        len = rp[rb + 1] - s;
    }
    int ml = len;
    ml = max(ml, __shfl_xor(ml, 16));
    ml = max(ml, __shfl_xor(ml, 32));

    float4 acc = make_float4(0.f, 0.f, 0.f, 0.f);
    for (int base = 0; base < ml; base += 16) {
        int2 p = make_int2(0, 0);
        int o = base + lq;
        if (o < len) p = pairs[s + o];
        int rem = len - base;
        rem = min(max(rem, 0), 16);
        int mr = rem;
        mr = max(mr, __shfl_xor(mr, 16));
        mr = max(mr, __shfl_xor(mr, 32));
        int cnt4 = (mr + 3) & ~3;
        for (int j = 0; j < cnt4; j += 4) {
            int c[4]; float v[4]; float4 f[4];
            #pragma unroll
            for (int q = 0; q < 4; ++q) {
                c[q] = __shfl(p.x, qb | (j + q));
                v[q] = __int_as_float(__shfl(p.y, qb | (j + q)));
            }
            #pragma unroll
            for (int q = 0; q < 4; ++q) {
                int cc = idx[c[q]];                 // needed by construction when v!=0
                cc = max(cc, 0);                    // OOB-pad edges map to 0 (v=0)
                f[q] = *(const float4*)&e1c[(size_t)cc * D + lq * 4];
            }
            #pragma unroll
            for (int q = 0; q < 4; ++q) {
                acc.x = fmaf(v[q], f[q].x, acc.x);
                acc.y = fmaf(v[q], f[q].y, acc.y);
                acc.z = fmaf(v[q], f[q].z, acc.z);
                acc.w = fmaf(v[q], f[q].w, acc.w);
            }
        }
    }
    if (valid) {
        *(float4*)&side2c[(size_t)r * D + lq * 4] = acc;
        *(float4*)&egoc[(size_t)r * D + lq * 4] =
            *(const float4*)&e1c[(size_t)cr * D + lq * 4];
    }
}

// ---------------- Tiled transform ----------------
__global__ __launch_bounds__(256) void transform_k(
    const float* __restrict__ S, const float* __restrict__ Eb,
    const float* __restrict__ Wg, const float* __restrict__ bg,
    const float* __restrict__ Wb, const float* __restrict__ bb,
    float* __restrict__ out, const int* __restrict__ list,
    const int* __restrict__ Mptr, int nrows)
{
    __shared__ __align__(16) float sWg[D * D];
    __shared__ __align__(16) float sWb[D * D];
    __shared__ __align__(16) float sAT[D][SPAD];
    __shared__ __align__(16) float sBT[D][SPAD];

    int nr = Mptr ? Mptr[0] : nrows;
    int t  = threadIdx.x;
    int tc = t & 15;
    int tr = t >> 4;
    int r0 = blockIdx.x * 64;
    if (r0 >= nr) return;

    for (int i = t; i < D * D; i += 256) {
        sWg[i] = Wg[i];
        sWb[i] = Wb[i];
    }
    for (int itr = 0; itr < 4; ++itr) {
        int rr  = itr * 16 + (t >> 4);
        int row = r0 + rr;
        float4 sv = make_float4(0.f, 0.f, 0.f, 0.f);
        float4 ev = sv;
        if (row < nr) {
            sv = *(const float4*)&S[(size_t)row * D + tc * 4];
            int er = list ? list[row] : row;
            ev = *(const float4*)&Eb[(size_t)er * D + tc * 4];
        }
        sAT[tc * 4 + 0][rr] = sv.x;
        sAT[tc * 4 + 1][rr] = sv.y;
        sAT[tc * 4 + 2][rr] = sv.z;
        sAT[tc * 4 + 3][rr] = sv.w;
        sBT[tc * 4 + 0][rr] = sv.x * ev.x;
        sBT[tc * 4 + 1][rr] = sv.y * ev.y;
        sBT[tc * 4 + 2][rr] = sv.z * ev.z;
        sBT[tc * 4 + 3][rr] = sv.w * ev.w;
    }
    __syncthreads();

    float acc[4][4] = {};
    for (int k = 0; k < D; ++k) {
        float4 a4 = *(const float4*)&sAT[k][tr * 4];
        float4 b4 = *(const float4*)&sBT[k][tr * 4];
        float4 g4 = *(const float4*)&sWg[k * D + tc * 4];
        float4 w4 = *(const float4*)&sWb[k * D + tc * 4];
        float av[4] = {a4.x, a4.y, a4.z, a4.w};
        float bv[4] = {b4.x, b4.y, b4.z, b4.w};
        float gv[4] = {g4.x, g4.y, g4.z, g4.w};
        float wv[4] = {w4.x, w4.y, w4.z, w4.w};
        #pragma unroll
        for (int i = 0; i < 4; ++i)
            #pragma unroll
            for (int j = 0; j < 4; ++j)
                acc[i][j] = fmaf(av[i], gv[j], fmaf(bv[i], wv[j], acc[i][j]));
    }

    float4 bgv = *(const float4*)&bg[tc * 4];
    float4 bbv = *(const float4*)&bb[tc * 4];
    float bias[4] = {bgv.x + bbv.x, bgv.y + bbv.y, bgv.z + bbv.z, bgv.w + bbv.w};

    float vv[4][4];
    float ss[4] = {0.f, 0.f, 0.f, 0.f};
    #pragma unroll
    for (int i = 0; i < 4; ++i) {
        #pragma unroll
        for (int j = 0; j < 4; ++j) {
            float v = acc[i][j] + bias[j];
            v = (v > 0.0f) ? v : 0.2f * v;
            vv[i][j] = v;
            ss[i] += v * v;
        }
    }
    #pragma unroll
    for (int i = 0; i < 4; ++i) {
        #pragma unroll
        for (int off = 1; off < 16; off <<= 1)
            ss[i] += __shfl_xor(ss[i], off);
    }
    #pragma unroll
    for (int i = 0; i < 4; ++i) {
        int row = r0 + tr * 4 + i;
        if (row < nr) {
            float inv = 1.0f / fmaxf(sqrtf(ss[i]), 1e-12f);
            float4 o = make_float4(vv[i][0] * inv, vv[i][1] * inv,
                                   vv[i][2] * inv, vv[i][3] * inv);
            *(float4*)&out[(size_t)row * D + tc * 4] = o;
        }
    }
}

// ---------------- Readout ----------------
__global__ __launch_bounds__(256) void gamma_k(
    const float* __restrict__ x, const float* __restrict__ e1c,
    const int* __restrict__ idx, const float* __restrict__ e2c,
    const int* __restrict__ users, const int* __restrict__ items,
    float* __restrict__ gamma, int batch)
{
    int gtid = blockIdx.x * blockDim.x + threadIdx.x;
    int wave = gtid >> 6;
    int lane = threadIdx.x & 63;
    if (wave >= batch) return;
    size_t uu = (size_t)users[wave];
    size_t tt = (size_t)(N_USERS_C + items[wave]);
    float acc = x[uu * D + lane] * x[tt * D + lane]
              + e1c[(size_t)idx[uu] * D + lane] * e1c[(size_t)idx[tt] * D + lane]
              + e2c[(size_t)wave * D + lane] * e2c[(size_t)(batch + wave) * D + lane];
    #pragma unroll
    for (int off = 1; off < 64; off <<= 1) acc += __shfl_xor(acc, off);
    if (lane == 0) gamma[wave] = acc;
}

extern "C" void kernel_launch(void* const* d_in, const int* in_sizes, int n_in,
                              void* d_out, int out_size, void* d_ws, size_t ws_size,
                              hipStream_t stream) {
    const int*   rows  = (const int*)d_in[0];
    const int*   cols  = (const int*)d_in[1];
    const float* vals  = (const float*)d_in[2];
    const float* x     = (const float*)d_in[3];
    const int*   users = (const int*)d_in[4];
    const int*   items = (const int*)d_in[5];
    const float* Wg0 = (const float*)d_in[6];
    const float* bg0 = (const float*)d_in[7];
    const float* Wb0 = (const float*)d_in[8];
    const float* bb0 = (const float*)d_in[9];
    const float* Wg1 = (const float*)d_in[10];
    const float* bg1 = (const float*)d_in[11];
    const float* Wb1 = (const float*)d_in[12];
    const float* bb1 = (const float*)d_in[13];

    int nnz   = in_sizes[0];
    int batch = in_sizes[4];
    float* out = (float*)d_out;

    size_t emb = (size_t)N_NODES_C * D;
    float* A      = (float*)d_ws;                  // e1c [M x 64]
    float* Sbuf   = A + emb;                       // side_c; aliases pairs1 / layer2 compacts
    int*   bcur   = (int*)(Sbuf + emb);            // NB*CPAD
    int*   rp     = bcur + NB * CPAD;              // NB*65 (+pad)
    int*   idx    = rp + NB * 65 + 2;              // [N]
    int*   list   = idx + N_NODES_C;               // [N]
    int*   bsum   = list + N_NODES_C;              // [1024]
    int*   Mptr   = bsum + 1024;                   // [4]
    int*   scnt   = Mptr + 4;                      // [NSUP*S1B]
    unsigned char* need = (unsigned char*)(scnt + NSUP * S1B);   // [N]
    unsigned char* samp = need + N_NODES_C;                      // [N]
    int2*  pairs  = (int2*)(((size_t)(samp + N_NODES_C) + 15) & ~(size_t)15);  // NB*FCAP

    int2*  pairs1 = (int2*)Sbuf;                   // build-time only (36.4MB < 38.4MB)
    float* side2c = Sbuf;                          // layer-2 compacts (after s2 consumed pairs1)
    float* egoc   = Sbuf + (size_t)2 * 2048 * D;
    float* e2c    = egoc + (size_t)2 * 2048 * D;

    // --- needed-set mark + compact ---
    hipMemsetAsync(need, 0, 2 * N_NODES_C, stream);
    mark1_k<<<(2 * batch + 255) / 256, 256, 0, stream>>>(users, items, samp, need, batch);
    mark2_k<<<1024, 256, 0, stream>>>(rows, cols, samp, need, nnz);
    scan1_k<<<NSCAN, 1024, 0, stream>>>(need, idx, bsum, N_NODES_C);
    scanB_k<<<(N_NODES_C + 255) / 256, 256, 0, stream>>>(bsum, idx, need, list, bcur, Mptr, N_NODES_C);

    // --- bucket build: private fragments (no global atomics in s1) ---
    s1_k<<<S1B, 512, 0, stream>>>(rows, cols, vals, idx, pairs1, scnt, nnz);
    s2_k<<<NSUP * BPS, 256, 0, stream>>>(scnt, pairs1, bcur, pairs);
    sortb_k<<<NB, 256, 0, stream>>>(bcur, pairs, rp);

    // --- Layer 1 over M needed rows (quarter-wave gather; worst-case grid) ---
    gather1_k<<<(N_NODES_C / 4 * 64 + 255) / 256, 256, 0, stream>>>(
        rp, pairs, x, Sbuf, Mptr);
    transform_k<<<(N_NODES_C + 63) / 64, 256, 0, stream>>>(
        Sbuf, x, Wg0, bg0, Wb0, bb0, A, list, Mptr, 0);

    // --- Layer 2 (sampled 2*batch rows) ---
    gather2_k<<<(2 * batch / 4 * 64 + 255) / 256, 256, 0, stream>>>(
        rp, pairs, A, idx, side2c, egoc, users, items, batch);
    transform_k<<<(2 * batch + 63) / 64, 256, 0, stream>>>(
        side2c, egoc, Wg1, bg1, Wb1, bb1, e2c, nullptr, nullptr, 2 * batch);

    // --- Readout ---
    gamma_k<<<(batch * 64 + 255) / 256, 256, 0, stream>>>(
        x, A, idx, e2c, users, items, out, batch);
}

// Round 15
// 254.078 us; speedup vs baseline: 1.8388x; 1.0317x over previous
//
#include <hip/hip_runtime.h>

#define N_USERS_C 100000
#define N_NODES_C 150000
#define D 64
#define NB 2344              // ceil(150000/64) fine buckets (compact-row space)
#define NSUP 74              // ceil(150000/2048) super buckets
#define CPAD 16              // global cursor padding: 1 int per 64B line
#define SPAD 68              // transform transposed-tile row stride
#define FCAP 1536            // fixed fine-bucket capacity (mean ~1030)
#define S1B 256              // s1 blocks
#define FRAG 240             // per-(block,super) fragment capacity (mean 128, +10 sigma)
#define S2CAP 2560           // s2 per-block staging capacity
#define BPS 16               // blocks per super in s2
#define FPB (S1B / BPS)      // fragments per s2 block = 16
#define NSCAN 147            // ceil(150000/1024)
#define MARK 1               // "marked" byte; ws poison is 0xAA so no zeroing needed

// ---------------- Needed-set marking (no memset: poison 0xAA != MARK) ----------------
__global__ __launch_bounds__(256) void mark1_k(
    const int* __restrict__ u, const int* __restrict__ it,
    unsigned char* __restrict__ samp, unsigned char* __restrict__ need, int batch)
{
    int i = blockIdx.x * blockDim.x + threadIdx.x;
    if (i >= 2 * batch) return;
    int n = (i < batch) ? u[i] : N_USERS_C + it[i - batch];
    samp[n] = MARK;
    need[n] = MARK;
}

__global__ __launch_bounds__(256) void mark2_k(
    const int* __restrict__ rows, const int* __restrict__ cols,
    const unsigned char* __restrict__ samp, unsigned char* __restrict__ need, int nnz)
{
    int gtid = blockIdx.x * blockDim.x + threadIdx.x;
    int stride = gridDim.x * blockDim.x;
    for (int e = gtid; e < nnz; e += stride)
        if (samp[rows[e]] == MARK) need[cols[e]] = MARK;
}

// ---------------- scan1: per-block scan of need flags ----------------
__global__ __launch_bounds__(1024) void scan1_k(
    const unsigned char* __restrict__ need, int* __restrict__ part,
    int* __restrict__ bsum, int n)
{
    __shared__ int wsum[16];
    int i = blockIdx.x * 1024 + threadIdx.x;
    int lane = threadIdx.x & 63, wid = threadIdx.x >> 6;
    int v = (i < n && need[i] == MARK) ? 1 : 0;
    int incl = v;
    #pragma unroll
    for (int off = 1; off < 64; off <<= 1) {
        int t = __shfl_up(incl, off);
        if (lane >= off) incl += t;
    }
    if (lane == 63) wsum[wid] = incl;
    __syncthreads();
    int woff = 0;
    for (int w = 0; w < wid; ++w) woff += wsum[w];
    if (i < n) part[i] = woff + incl - v;
    if (threadIdx.x == 1023) bsum[blockIdx.x] = woff + incl;
}

// ---------------- scanB: local prefix of bsum + finalize idx/list + cursors + Mptr ----------------
__global__ __launch_bounds__(256) void scanB_k(
    const int* __restrict__ bsum, int* __restrict__ idx,
    const unsigned char* __restrict__ need, int* __restrict__ list,
    int* __restrict__ bcur, int* __restrict__ Mptr, int n)
{
    __shared__ int pre[NSCAN + 1];
    __shared__ int raw[NSCAN];
    int t = threadIdx.x;
    if (t < NSCAN) raw[t] = bsum[t];
    __syncthreads();
    if (t == 0) {
        int run = 0;
        for (int k = 0; k < NSCAN; ++k) { pre[k] = run; run += raw[k]; }
        pre[NSCAN] = run;
    }
    __syncthreads();
    int i = blockIdx.x * blockDim.x + t;
    if (i < NB) bcur[i * CPAD] = i * FCAP;
    if (blockIdx.x == 0 && t == 0) Mptr[0] = pre[NSCAN];
    if (i >= n) return;
    int val = idx[i] + pre[i >> 10];
    if (need[i] == MARK) { idx[i] = val; list[val] = i; }
    else idx[i] = -1;
}

// ---------------- S1: single-pass scatter into private per-(block,super) fragments ----------------
__global__ __launch_bounds__(512) void s1_k(
    const int* __restrict__ rows, const int* __restrict__ cols,
    const float* __restrict__ vals, const int* __restrict__ idx,
    int2* __restrict__ pairs1, int* __restrict__ scnt, int nnz)
{
    __shared__ int lcur[NSUP];
    int t = threadIdx.x;
    for (int i = t; i < NSUP; i += 512) lcur[i] = 0;
    __syncthreads();
    int b = blockIdx.x;
    int per = (nnz + S1B - 1) / S1B;
    int s = b * per;
    int e = min(nnz, s + per);
    for (int i = s + t; i < e; i += 512) {
        int ci = idx[rows[i]];
        if (ci < 0) continue;
        int sp = ci >> 11;
        int k = atomicAdd(&lcur[sp], 1);
        pairs1[(size_t)sp * (S1B * FRAG) + b * FRAG + k] =
            make_int2(((ci & 2047) << 18) | cols[i], __float_as_int(vals[i]));
    }
    __syncthreads();
    for (int i = t; i < NSUP; i += 512) scnt[i * S1B + b] = lcur[i];
}

// ---------------- S2: gather fragments of one super-part, scatter to fine buckets ----------------
__global__ __launch_bounds__(256) void s2_k(
    const int* __restrict__ scnt, const int2* __restrict__ pairs1,
    int* __restrict__ bcurP, int2* __restrict__ pairs)
{
    __shared__ int2 sbuf[S2CAP];
    __shared__ int fcnt[32], fcur[32], gb[32];
    int sp = blockIdx.x / BPS, part = blockIdx.x % BPS;
    int t = threadIdx.x;
    if (t < 32) { fcnt[t] = 0; fcur[t] = 0; }
    __syncthreads();
    int base = 0;
    for (int fi = 0; fi < FPB; ++fi) {
        int b = part * FPB + fi;
        int m = scnt[sp * S1B + b];
        const int2* src = &pairs1[(size_t)sp * (S1B * FRAG) + b * FRAG];
        for (int i = t; i < m; i += 256) {
            int2 p = src[i];
            sbuf[base + i] = p;
            atomicAdd(&fcnt[(p.x >> 18) >> 6], 1);
        }
        base += m;
    }
    __syncthreads();
    if (t < 32) {
        int c = fcnt[t];
        gb[t] = c ? atomicAdd(&bcurP[(sp * 32 + t) * CPAD], c) : 0;
    }
    __syncthreads();
    for (int i = t; i < base; i += 256) {
        int2 p = sbuf[i];
        int ris = p.x >> 18;
        int f = ris >> 6;
        int k = atomicAdd(&fcur[f], 1);
        pairs[gb[f] + k] = make_int2(((ris & 63) << 18) | (p.x & 0x3FFFF), p.y);
    }
}

// ---------------- Per-bucket LDS counting sort -> per-row ranges ----------------
__global__ __launch_bounds__(256) void sortb_k(
    const int* __restrict__ bcurP, int2* __restrict__ pairs,
    int* __restrict__ rp)
{
    __shared__ int2 buf[FCAP];
    __shared__ int cnt[64];
    __shared__ int cur[64];
    int b = blockIdx.x;
    int s = b * FCAP;
    int e = bcurP[b * CPAD];
    int m = e - s;
    int t = threadIdx.x;
    if (t < 64) cnt[t] = 0;
    __syncthreads();
    for (int i = t; i < m; i += 256) {
        int2 p = pairs[s + i];
        buf[i] = p;
        atomicAdd(&cnt[p.x >> 18], 1);
    }
    __syncthreads();
    if (t < 64) {
        int v = cnt[t];
        int incl = v;
        #pragma unroll
        for (int o = 1; o < 64; o <<= 1) {
            int u = __shfl_up(incl, o);
            if (t >= o) incl += u;
        }
        cur[t] = incl - v;
        rp[b * 65 + t] = s + incl - v;
        if (t == 63) rp[b * 65 + 64] = s + incl;
    }
    __syncthreads();
    for (int i = t; i < m; i += 256) {
        int2 p = buf[i];
        int dst = atomicAdd(&cur[p.x >> 18], 1);
        pairs[s + dst] = make_int2(p.x & 0x3FFFF, p.y);
    }
}

// ---------------- Layer-1 gather: quarter-wave float4, unroll-8 ----------------
__global__ __launch_bounds__(256) void gather1_k(
    const int* __restrict__ rp, const int2* __restrict__ pairs,
    const float* __restrict__ x, float* __restrict__ side,
    const int* __restrict__ Mptr)
{
    int gtid = blockIdx.x * blockDim.x + threadIdx.x;
    int wave = gtid >> 6;
    int lane = threadIdx.x & 63;
    int M = Mptr[0];
    if (wave * 4 >= M) return;
    int lq = lane & 15;
    int qb = lane & 48;
    int row = wave * 4 + (lane >> 4);
    int valid = row < M;
    int s = 0, len = 0;
    if (valid) {
        int rb = (row >> 6) * 65 + (row & 63);
        s = rp[rb];
        len = rp[rb + 1] - s;
    }
    int ml = len;
    ml = max(ml, __shfl_xor(ml, 16));
    ml = max(ml, __shfl_xor(ml, 32));

    float4 acc = make_float4(0.f, 0.f, 0.f, 0.f);
    for (int base = 0; base < ml; base += 16) {
        int2 p = make_int2(0, 0);
        int o = base + lq;
        if (o < len) p = pairs[s + o];
        int rem = len - base;
        rem = min(max(rem, 0), 16);
        int mr = rem;
        mr = max(mr, __shfl_xor(mr, 16));
        mr = max(mr, __shfl_xor(mr, 32));
        int cnt8 = (mr + 7) & ~7;
        for (int j = 0; j < cnt8; j += 8) {
            int c[8]; float v[8]; float4 f[8];
            #pragma unroll
            for (int q = 0; q < 8; ++q) {
                c[q] = __shfl(p.x, qb | (j + q));
                v[q] = __int_as_float(__shfl(p.y, qb | (j + q)));
            }
            #pragma unroll
            for (int q = 0; q < 8; ++q)
                f[q] = *(const float4*)&x[(size_t)c[q] * D + lq * 4];
            #pragma unroll
            for (int q = 0; q < 8; ++q) {
                acc.x = fmaf(v[q], f[q].x, acc.x);
                acc.y = fmaf(v[q], f[q].y, acc.y);
                acc.z = fmaf(v[q], f[q].z, acc.z);
                acc.w = fmaf(v[q], f[q].w, acc.w);
            }
        }
    }
    if (valid) *(float4*)&side[(size_t)row * D + lq * 4] = acc;
}

// ---------------- Layer-2 gather (sampled): quarter-wave float4, unroll-8, idx indirection ----------------
__global__ __launch_bounds__(256) void gather2_k(
    const int* __restrict__ rp, const int2* __restrict__ pairs,
    const float* __restrict__ e1c, const int* __restrict__ idx,
    float* __restrict__ side2c, float* __restrict__ egoc,
    const int* __restrict__ u, const int* __restrict__ it, int batch)
{
    int gtid = blockIdx.x * blockDim.x + threadIdx.x;
    int wave = gtid >> 6;
    int lane = threadIdx.x & 63;
    int nr = 2 * batch;
    if (wave * 4 >= nr) return;
    int lq = lane & 15;
    int qb = lane & 48;
    int r = wave * 4 + (lane >> 4);
    int valid = r < nr;
    int s = 0, len = 0, cr = 0;
    if (valid) {
        int n = (r < batch) ? u[r] : N_USERS_C + it[r - batch];
        cr = idx[n];
        int rb = (cr >> 6) * 65 + (cr & 63);
        s = rp[rb];
        len = rp[rb + 1] - s;
    }
    int ml = len;
    ml = max(ml, __shfl_xor(ml, 16));
    ml = max(ml, __shfl_xor(ml, 32));

    float4 acc = make_float4(0.f, 0.f, 0.f, 0.f);
    for (int base = 0; base < ml; base += 16) {
        int2 p = make_int2(0, 0);
        int o = base + lq;
        if (o < len) p = pairs[s + o];
        int rem = len - base;
        rem = min(max(rem, 0), 16);
        int mr = rem;
        mr = max(mr, __shfl_xor(mr, 16));
        mr = max(mr, __shfl_xor(mr, 32));
        int cnt8 = (mr + 7) & ~7;
        for (int j = 0; j < cnt8; j += 8) {
            int c[8]; float v[8]; float4 f[8];
            #pragma unroll
            for (int q = 0; q < 8; ++q) {
                c[q] = __shfl(p.x, qb | (j + q));
                v[q] = __int_as_float(__shfl(p.y, qb | (j + q)));
            }
            #pragma unroll
            for (int q = 0; q < 8; ++q) {
                int cc = idx[c[q]];                 // needed by construction when v!=0
                cc = max(cc, 0);                    // OOB-pad edges map to row 0 (v=0)
                f[q] = *(const float4*)&e1c[(size_t)cc * D + lq * 4];
            }
            #pragma unroll
            for (int q = 0; q < 8; ++q) {
                acc.x = fmaf(v[q], f[q].x, acc.x);
                acc.y = fmaf(v[q], f[q].y, acc.y);
                acc.z = fmaf(v[q], f[q].z, acc.z);
                acc.w = fmaf(v[q], f[q].w, acc.w);
            }
        }
    }
    if (valid) {
        *(float4*)&side2c[(size_t)r * D + lq * 4] = acc;
        *(float4*)&egoc[(size_t)r * D + lq * 4] =
            *(const float4*)&e1c[(size_t)cr * D + lq * 4];
    }
}

// ---------------- Tiled transform ----------------
__global__ __launch_bounds__(256) void transform_k(
    const float* __restrict__ S, const float* __restrict__ Eb,
    const float* __restrict__ Wg, const float* __restrict__ bg,
    const float* __restrict__ Wb, const float* __restrict__ bb,
    float* __restrict__ out, const int* __restrict__ list,
    const int* __restrict__ Mptr, int nrows)
{
    __shared__ __align__(16) float sWg[D * D];
    __shared__ __align__(16) float sWb[D * D];
    __shared__ __align__(16) float sAT[D][SPAD];
    __shared__ __align__(16) float sBT[D][SPAD];

    int nr = Mptr ? Mptr[0] : nrows;
    int t  = threadIdx.x;
    int tc = t & 15;
    int tr = t >> 4;
    int r0 = blockIdx.x * 64;
    if (r0 >= nr) return;

    for (int i = t; i < D * D; i += 256) {
        sWg[i] = Wg[i];
        sWb[i] = Wb[i];
    }
    for (int itr = 0; itr < 4; ++itr) {
        int rr  = itr * 16 + (t >> 4);
        int row = r0 + rr;
        float4 sv = make_float4(0.f, 0.f, 0.f, 0.f);
        float4 ev = sv;
        if (row < nr) {
            sv = *(const float4*)&S[(size_t)row * D + tc * 4];
            int er = list ? list[row] : row;
            ev = *(const float4*)&Eb[(size_t)er * D + tc * 4];
        }
        sAT[tc * 4 + 0][rr] = sv.x;
        sAT[tc * 4 + 1][rr] = sv.y;
        sAT[tc * 4 + 2][rr] = sv.z;
        sAT[tc * 4 + 3][rr] = sv.w;
        sBT[tc * 4 + 0][rr] = sv.x * ev.x;
        sBT[tc * 4 + 1][rr] = sv.y * ev.y;
        sBT[tc * 4 + 2][rr] = sv.z * ev.z;
        sBT[tc * 4 + 3][rr] = sv.w * ev.w;
    }
    __syncthreads();

    float acc[4][4] = {};
    for (int k = 0; k < D; ++k) {
        float4 a4 = *(const float4*)&sAT[k][tr * 4];
        float4 b4 = *(const float4*)&sBT[k][tr * 4];
        float4 g4 = *(const float4*)&sWg[k * D + tc * 4];
        float4 w4 = *(const float4*)&sWb[k * D + tc * 4];
        float av[4] = {a4.x, a4.y, a4.z, a4.w};
        float bv[4] = {b4.x, b4.y, b4.z, b4.w};
        float gv[4] = {g4.x, g4.y, g4.z, g4.w};
        float wv[4] = {w4.x, w4.y, w4.z, w4.w};
        #pragma unroll
        for (int i = 0; i < 4; ++i)
            #pragma unroll
            for (int j = 0; j < 4; ++j)
                acc[i][j] = fmaf(av[i], gv[j], fmaf(bv[i], wv[j], acc[i][j]));
    }

    float4 bgv = *(const float4*)&bg[tc * 4];
    float4 bbv = *(const float4*)&bb[tc * 4];
    float bias[4] = {bgv.x + bbv.x, bgv.y + bbv.y, bgv.z + bbv.z, bgv.w + bbv.w};

    float vv[4][4];
    float ss[4] = {0.f, 0.f, 0.f, 0.f};
    #pragma unroll
    for (int i = 0; i < 4; ++i) {
        #pragma unroll
        for (int j = 0; j < 4; ++j) {
            float v = acc[i][j] + bias[j];
            v = (v > 0.0f) ? v : 0.2f * v;
            vv[i][j] = v;
            ss[i] += v * v;
        }
    }
    #pragma unroll
    for (int i = 0; i < 4; ++i) {
        #pragma unroll
        for (int off = 1; off < 16; off <<= 1)
            ss[i] += __shfl_xor(ss[i], off);
    }
    #pragma unroll
    for (int i = 0; i < 4; ++i) {
        int row = r0 + tr * 4 + i;
        if (row < nr) {
            float inv = 1.0f / fmaxf(sqrtf(ss[i]), 1e-12f);
            float4 o = make_float4(vv[i][0] * inv, vv[i][1] * inv,
                                   vv[i][2] * inv, vv[i][3] * inv);
            *(float4*)&out[(size_t)row * D + tc * 4] = o;
        }
    }
}

// ---------------- Readout ----------------
__global__ __launch_bounds__(256) void gamma_k(
    const float* __restrict__ x, const float* __restrict__ e1c,
    const int* __restrict__ idx, const float* __restrict__ e2c,
    const int* __restrict__ users, const int* __restrict__ items,
    float* __restrict__ gamma, int batch)
{
    int gtid = blockIdx.x * blockDim.x + threadIdx.x;
    int wave = gtid >> 6;
    int lane = threadIdx.x & 63;
    if (wave >= batch) return;
    size_t uu = (size_t)users[wave];
    size_t tt = (size_t)(N_USERS_C + items[wave]);
    float acc = x[uu * D + lane] * x[tt * D + lane]
              + e1c[(size_t)idx[uu] * D + lane] * e1c[(size_t)idx[tt] * D + lane]
              + e2c[(size_t)wave * D + lane] * e2c[(size_t)(batch + wave) * D + lane];
    #pragma unroll
    for (int off = 1; off < 64; off <<= 1) acc += __shfl_xor(acc, off);
    if (lane == 0) gamma[wave] = acc;
}

extern "C" void kernel_launch(void* const* d_in, const int* in_sizes, int n_in,
                              void* d_out, int out_size, void* d_ws, size_t ws_size,
                              hipStream_t stream) {
    const int*   rows  = (const int*)d_in[0];
    const int*   cols  = (const int*)d_in[1];
    const float* vals  = (const float*)d_in[2];
    const float* x     = (const float*)d_in[3];
    const int*   users = (const int*)d_in[4];
    const int*   items = (const int*)d_in[5];
    const float* Wg0 = (const float*)d_in[6];
    const float* bg0 = (const float*)d_in[7];
    const float* Wb0 = (const float*)d_in[8];
    const float* bb0 = (const float*)d_in[9];
    const float* Wg1 = (const float*)d_in[10];
    const float* bg1 = (const float*)d_in[11];
    const float* Wb1 = (const float*)d_in[12];
    const float* bb1 = (const float*)d_in[13];

    int nnz   = in_sizes[0];
    int batch = in_sizes[4];
    float* out = (float*)d_out;

    size_t emb = (size_t)N_NODES_C * D;
    float* A      = (float*)d_ws;                  // e1c [M x 64]
    float* Sbuf   = A + emb;                       // side_c; aliases pairs1 / layer2 compacts
    int*   bcur   = (int*)(Sbuf + emb);            // NB*CPAD
    int*   rp     = bcur + NB * CPAD;              // NB*65 (+pad)
    int*   idx    = rp + NB * 65 + 2;              // [N]
    int*   list   = idx + N_NODES_C;               // [N]
    int*   bsum   = list + N_NODES_C;              // [1024]
    int*   Mptr   = bsum + 1024;                   // [4]
    int*   scnt   = Mptr + 4;                      // [NSUP*S1B]
    unsigned char* need = (unsigned char*)(scnt + NSUP * S1B);   // [N]
    unsigned char* samp = need + N_NODES_C;                      // [N]
    int2*  pairs  = (int2*)(((size_t)(samp + N_NODES_C) + 15) & ~(size_t)15);  // NB*FCAP

    int2*  pairs1 = (int2*)Sbuf;                   // build-time only (36.4MB < 38.4MB)
    float* side2c = Sbuf;                          // layer-2 compacts (after s2 consumed pairs1)
    float* egoc   = Sbuf + (size_t)2 * 2048 * D;
    float* e2c    = egoc + (size_t)2 * 2048 * D;

    // --- needed-set mark + compact (no memset: poison-as-unmarked) ---
    mark1_k<<<(2 * batch + 255) / 256, 256, 0, stream>>>(users, items, samp, need, batch);
    mark2_k<<<1024, 256, 0, stream>>>(rows, cols, samp, need, nnz);
    scan1_k<<<NSCAN, 1024, 0, stream>>>(need, idx, bsum, N_NODES_C);
    scanB_k<<<(N_NODES_C + 255) / 256, 256, 0, stream>>>(bsum, idx, need, list, bcur, Mptr, N_NODES_C);

    // --- bucket build: private fragments (no global atomics in s1) ---
    s1_k<<<S1B, 512, 0, stream>>>(rows, cols, vals, idx, pairs1, scnt, nnz);
    s2_k<<<NSUP * BPS, 256, 0, stream>>>(scnt, pairs1, bcur, pairs);
    sortb_k<<<NB, 256, 0, stream>>>(bcur, pairs, rp);

    // --- Layer 1 over M needed rows (quarter-wave gather; worst-case grid) ---
    gather1_k<<<(N_NODES_C / 4 * 64 + 255) / 256, 256, 0, stream>>>(
        rp, pairs, x, Sbuf, Mptr);
    transform_k<<<(N_NODES_C + 63) / 64, 256, 0, stream>>>(
        Sbuf, x, Wg0, bg0, Wb0, bb0, A, list, Mptr, 0);

    // --- Layer 2 (sampled 2*batch rows) ---
    gather2_k<<<(2 * batch / 4 * 64 + 255) / 256, 256, 0, stream>>>(
        rp, pairs, A, idx, side2c, egoc, users, items, batch);
    transform_k<<<(2 * batch + 63) / 64, 256, 0, stream>>>(
        side2c, egoc, Wg1, bg1, Wb1, bb1, e2c, nullptr, nullptr, 2 * batch);

    // --- Readout ---
    gamma_k<<<(batch * 64 + 255) / 256, 256, 0, stream>>>(
        x, A, idx, e2c, users, items, out, batch);
}